// Round 1
// 2745.235 us; speedup vs baseline: 1.0050x; 1.0050x over previous
//
#include <hip/hip_runtime.h>

typedef unsigned short u16;
typedef unsigned int u32;
typedef __bf16 bf16x8 __attribute__((ext_vector_type(8)));
typedef float f32x4 __attribute__((ext_vector_type(4)));

#define EOS_ID 50256
#define DM 768
#define NH 12
#define DHD 64
#define SEQ 1024
#define NB 2
#define NLAYERS 4
#define DFF 3072
#define NV 50257
#define NTOK 2048
#define QKVW 2304

__device__ __forceinline__ float bf2f(u16 u) {
  union { float f; u32 u; } x; x.u = ((u32)u) << 16; return x.f;
}
__device__ __forceinline__ u16 f2bf(float f) {
  union { float f; u32 u; } x; x.f = f;
  u32 u = x.u;
  u += 0x7fffu + ((u >> 16) & 1u);   // round-to-nearest-even
  return (u16)(u >> 16);
}
__device__ __forceinline__ u32 pack2(float a, float b) {
  return (u32)f2bf(a) | ((u32)f2bf(b) << 16);
}

// ---------- packed-segment scan ----------
__global__ __launch_bounds__(1024)
void scan_kernel(const int* __restrict__ ids, int* __restrict__ rel, int* __restrict__ seg) {
  __shared__ int sm[1024];
  __shared__ int ss[1024];
  const int b = blockIdx.x, t = threadIdx.x;
  const int e = (ids[b * SEQ + t] == EOS_ID) ? 1 : 0;
  sm[t] = e ? t : 0;
  ss[t] = e;
  __syncthreads();
  for (int o = 1; o < 1024; o <<= 1) {
    int vm = 0, vs = 0;
    if (t >= o) { vm = sm[t - o]; vs = ss[t - o]; }
    __syncthreads();
    if (t >= o) { if (vm > sm[t]) sm[t] = vm; ss[t] += vs; }
    __syncthreads();
  }
  rel[b * SEQ + t] = t - sm[t];
  seg[b * SEQ + t] = ss[t];
}

// ---------- embedding: x = tok[id]*sqrt(D) + pos[rel] (fp32 in, fp32 out) ----------
__global__ __launch_bounds__(256)
void embed_kernel(const int* __restrict__ ids, const int* __restrict__ rel,
                  const float* __restrict__ tok, const float* __restrict__ pos,
                  float* __restrict__ x) {
  const int row = blockIdx.x;
  const int id = ids[row];
  const int r = rel[row];
  const float s = 27.712812921102035f;  // sqrt(768)
  for (int d = threadIdx.x; d < DM; d += 256)
    x[(size_t)row * DM + d] = tok[(size_t)id * DM + d] * s + pos[(size_t)r * DM + d];
}

// ---------- layernorm (fp32 in, fp32 gamma/beta) -> bf16 out ----------
__global__ __launch_bounds__(256)
void ln_kernel(const float* __restrict__ x, const float* __restrict__ g,
               const float* __restrict__ b, u16* __restrict__ out) {
  const int row = blockIdx.x, t = threadIdx.x;
  const int wave = t >> 6, lane = t & 63;
  const float* xr = x + (size_t)row * DM;
  float v0 = xr[t], v1 = xr[t + 256], v2 = xr[t + 512];
  __shared__ float red[4];
  float s = v0 + v1 + v2;
  for (int o = 32; o; o >>= 1) s += __shfl_down(s, o, 64);
  if (lane == 0) red[wave] = s;
  __syncthreads();
  const float mean = (red[0] + red[1] + red[2] + red[3]) * (1.f / DM);
  __syncthreads();
  const float a0 = v0 - mean, a1 = v1 - mean, a2 = v2 - mean;
  float s2 = a0 * a0 + a1 * a1 + a2 * a2;
  for (int o = 32; o; o >>= 1) s2 += __shfl_down(s2, o, 64);
  if (lane == 0) red[wave] = s2;
  __syncthreads();
  const float var = (red[0] + red[1] + red[2] + red[3]) * (1.f / DM);
  const float rstd = rsqrtf(var + 1e-5f);
  u16* orow = out + (size_t)row * DM;
  orow[t]       = f2bf(a0 * rstd * g[t]       + b[t]);
  orow[t + 256] = f2bf(a1 * rstd * g[t + 256] + b[t + 256]);
  orow[t + 512] = f2bf(a2 * rstd * g[t + 512] + b[t + 512]);
}

// ---------- repack Wq/Wk/Wv fp32 [H,D,DH] -> fused bf16 B^T [2304][768] ----------
__global__ __launch_bounds__(256)
void repack_qkv(const float* __restrict__ Wq, const float* __restrict__ Wk,
                const float* __restrict__ Wv, int layer, u16* __restrict__ out) {
  const int idx = blockIdx.x * 256 + threadIdx.x;
  if (idx >= QKVW * DM) return;
  const int n = idx / DM, k = idx % DM;
  const int sel = n / DM;
  const int hh = (n % DM) / DHD, dh = n % DHD;
  const float* W = (sel == 0) ? Wq : (sel == 1) ? Wk : Wv;
  out[idx] = f2bf(W[(((size_t)layer * NH + hh) * DM + k) * DHD + dh]);
}

__global__ __launch_bounds__(256)
void repack_bias(const float* __restrict__ bq, const float* __restrict__ bk,
                 const float* __restrict__ bv, int layer, float* __restrict__ out) {
  const int n = blockIdx.x * 256 + threadIdx.x;
  if (n >= QKVW) return;
  const int sel = n / DM;
  const int hh = (n % DM) / DHD, dh = n % DHD;
  const float* B = (sel == 0) ? bq : (sel == 1) ? bk : bv;
  out[n] = B[((size_t)layer * NH + hh) * DHD + dh];
}

// ---------- transpose fp32 [R][C] -> bf16 [C][R] (R,C multiples of 32) ----------
__global__ __launch_bounds__(256)
void transpose_f2b(const float* __restrict__ src, u16* __restrict__ dst, int R, int C) {
  __shared__ float tile[32][33];
  const int c0 = blockIdx.x * 32, r0 = blockIdx.y * 32;
  const int tx = threadIdx.x & 31, ty = threadIdx.x >> 5;
  for (int i = 0; i < 32; i += 8)
    tile[ty + i][tx] = src[(size_t)(r0 + ty + i) * C + c0 + tx];
  __syncthreads();
  for (int i = 0; i < 32; i += 8)
    dst[(size_t)(c0 + ty + i) * R + r0 + tx] = f2bf(tile[tx][ty + i]);
}

// ---------- fp32 -> bf16 ----------
__global__ __launch_bounds__(256)
void f2bf_kernel(const float* __restrict__ in, u16* __restrict__ out, int n) {
  const int i = blockIdx.x * 256 + threadIdx.x;
  if (i < n) out[i] = f2bf(in[i]);
}

// ---------- GEMM: C[M,N] = A[M,K] @ BT[N,K]^T (bf16 in, fp32 acc, fp32 bias) ----------
// EPI 0: bf16 = acc+bias ; EPI 1: fp32 += acc+bias (residual) ; EPI 2: bf16 gelu(acc+bias)
template <int EPI>
__global__ __launch_bounds__(256)
void gemm_bt(const u16* __restrict__ A, const u16* __restrict__ BT,
             const float* __restrict__ bias, void* __restrict__ out,
             const int M, const int N, const int K) {
  __shared__ u16 As[128 * 40];
  __shared__ u16 Bs[128 * 40];
  const int t = threadIdx.x;
  const int wave = t >> 6, lane = t & 63;
  const int l15 = lane & 15, quad = lane >> 4;
  const int wm = wave >> 1, wn = wave & 1;
  const int m0 = blockIdx.y * 128;
  const int n0 = blockIdx.x * 128;
  const int arow = t >> 2;
  const int acol = (t & 3) * 8;

  f32x4 acc[4][4] = {};

  for (int k0 = 0; k0 < K; k0 += 32) {
    __syncthreads();
    const uint4 a0 = *(const uint4*)(A + (size_t)(m0 + arow) * K + k0 + acol);
    const uint4 a1 = *(const uint4*)(A + (size_t)(m0 + arow + 64) * K + k0 + acol);
    const int r0 = n0 + arow, r1 = n0 + arow + 64;
    uint4 b0 = make_uint4(0, 0, 0, 0), b1 = make_uint4(0, 0, 0, 0);
    if (r0 < N) b0 = *(const uint4*)(BT + (size_t)r0 * K + k0 + acol);
    if (r1 < N) b1 = *(const uint4*)(BT + (size_t)r1 * K + k0 + acol);
    *(uint4*)&As[arow * 40 + acol] = a0;
    *(uint4*)&As[(arow + 64) * 40 + acol] = a1;
    *(uint4*)&Bs[arow * 40 + acol] = b0;
    *(uint4*)&Bs[(arow + 64) * 40 + acol] = b1;
    __syncthreads();
    bf16x8 af[4], bfr[4];
#pragma unroll
    for (int mt = 0; mt < 4; mt++)
      af[mt] = *(const bf16x8*)&As[(wm * 64 + mt * 16 + l15) * 40 + quad * 8];
#pragma unroll
    for (int nt = 0; nt < 4; nt++)
      bfr[nt] = *(const bf16x8*)&Bs[(wn * 64 + nt * 16 + l15) * 40 + quad * 8];
#pragma unroll
    for (int mt = 0; mt < 4; mt++)
#pragma unroll
      for (int nt = 0; nt < 4; nt++)
        acc[mt][nt] = __builtin_amdgcn_mfma_f32_16x16x32_bf16(af[mt], bfr[nt], acc[mt][nt], 0, 0, 0);
  }

#pragma unroll
  for (int nt = 0; nt < 4; nt++) {
    const int n = n0 + wn * 64 + nt * 16 + l15;
    if (n < N) {
      const float bvv = bias ? bias[n] : 0.f;
#pragma unroll
      for (int mt = 0; mt < 4; mt++) {
        const int mb = m0 + wm * 64 + mt * 16 + quad * 4;
#pragma unroll
        for (int r = 0; r < 4; r++) {
          const size_t idx = (size_t)(mb + r) * N + n;
          const float v = acc[mt][nt][r] + bvv;
          if (EPI == 0) {
            ((u16*)out)[idx] = f2bf(v);
          } else if (EPI == 1) {
            ((float*)out)[idx] += v;
          } else {
            const float gg = 0.5f * v * (1.f + erff(v * 0.70710678118654752f));
            ((u16*)out)[idx] = f2bf(gg);
          }
        }
      }
    }
  }
}

// ---------- final GEMM: out fp32 [M,N] = A(bf16)[M,K] @ tok(fp32)[N,K]^T ----------
// 1-D grid of (M/128)*(ceil(N/128)) blocks, XCD-swizzled so the 16 M-tile blocks
// sharing one N-tile of B run consecutively on the SAME XCD (B-tile fetched into
// exactly one L2, once). Epilogue staged through LDS so each wave-store writes
// 256 B contiguous (full L2 lines, no partial-line RMW).
__global__ __launch_bounds__(256)
void gemm_final(const u16* __restrict__ A, const float* __restrict__ BT,
                float* __restrict__ out, const int M, const int N, const int K) {
  __shared__ u16 smem[2 * 128 * 40];   // 20480 B: As | Bs, reused as fp32 scratch in epilogue
  u16* As = smem;
  u16* Bs = smem + 128 * 40;

  const int t = threadIdx.x;
  const int wave = t >> 6, lane = t & 63;
  const int l15 = lane & 15, quad = lane >> 4;
  const int wm = wave >> 1, wn = wave & 1;

  // XCD-aware swizzle: gridDim.x % 8 == 0 (16 * 393 = 6288). M-tile fastest.
  const int bid = blockIdx.x;
  const int nper = gridDim.x >> 3;          // blocks per XCD
  const int gt = (bid & 7) * nper + (bid >> 3);
  const int mtile = gt & 15;                // M/128 == 16
  const int ntile = gt >> 4;
  const int m0 = mtile * 128;
  const int n0 = ntile * 128;

  const int arow = t >> 2;
  const int acol = (t & 3) * 8;

  f32x4 acc[4][4] = {};

  for (int k0 = 0; k0 < K; k0 += 32) {
    __syncthreads();
    const uint4 a0 = *(const uint4*)(A + (size_t)(m0 + arow) * K + k0 + acol);
    const uint4 a1 = *(const uint4*)(A + (size_t)(m0 + arow + 64) * K + k0 + acol);
    const int r0 = n0 + arow, r1 = n0 + arow + 64;
    uint4 b0 = make_uint4(0, 0, 0, 0), b1 = make_uint4(0, 0, 0, 0);
    if (r0 < N) {
      const float4 f0 = *(const float4*)(BT + (size_t)r0 * K + k0 + acol);
      const float4 f1 = *(const float4*)(BT + (size_t)r0 * K + k0 + acol + 4);
      b0 = make_uint4(pack2(f0.x, f0.y), pack2(f0.z, f0.w), pack2(f1.x, f1.y), pack2(f1.z, f1.w));
    }
    if (r1 < N) {
      const float4 f0 = *(const float4*)(BT + (size_t)r1 * K + k0 + acol);
      const float4 f1 = *(const float4*)(BT + (size_t)r1 * K + k0 + acol + 4);
      b1 = make_uint4(pack2(f0.x, f0.y), pack2(f0.z, f0.w), pack2(f1.x, f1.y), pack2(f1.z, f1.w));
    }
    *(uint4*)&As[arow * 40 + acol] = a0;
    *(uint4*)&As[(arow + 64) * 40 + acol] = a1;
    *(uint4*)&Bs[arow * 40 + acol] = b0;
    *(uint4*)&Bs[(arow + 64) * 40 + acol] = b1;
    __syncthreads();
    bf16x8 af[4], bfr[4];
#pragma unroll
    for (int mt = 0; mt < 4; mt++)
      af[mt] = *(const bf16x8*)&As[(wm * 64 + mt * 16 + l15) * 40 + quad * 8];
#pragma unroll
    for (int nt = 0; nt < 4; nt++)
      bfr[nt] = *(const bf16x8*)&Bs[(wn * 64 + nt * 16 + l15) * 40 + quad * 8];
#pragma unroll
    for (int mt = 0; mt < 4; mt++)
#pragma unroll
      for (int nt = 0; nt < 4; nt++)
        acc[mt][nt] = __builtin_amdgcn_mfma_f32_16x16x32_bf16(af[mt], bfr[nt], acc[mt][nt], 0, 0, 0);
  }

  // ---- epilogue: stage per-mt slice (32 rows x 128 cols fp32, stride 132) in LDS,
  // then write with 64 consecutive lanes covering 256 B contiguous per store.
  float* sc = (float*)smem;  // needs 32*132*4 = 16896 B <= 20480 B
  for (int mt = 0; mt < 4; mt++) {
    __syncthreads();
#pragma unroll
    for (int nt = 0; nt < 4; nt++)
#pragma unroll
      for (int r = 0; r < 4; r++)
        sc[(wm * 16 + quad * 4 + r) * 132 + wn * 64 + nt * 16 + l15] = acc[mt][nt][r];
    __syncthreads();
#pragma unroll
    for (int it = 0; it < 16; it++) {
      const int lin = it * 256 + t;          // 0..4095
      const int s = lin >> 7;                // staged row 0..31
      const int c = lin & 127;               // col within tile
      const int grow = m0 + mt * 16 + (s & 15) + (s >> 4) * 64;
      const int gcol = n0 + c;
      if (gcol < N) out[(size_t)grow * N + gcol] = sc[s * 132 + c];
    }
  }
}

// ---------- attention: 4 query rows / block, scalar fp32, packed-segment mask ----------
__global__ __launch_bounds__(256)
void attn_kernel(const u16* __restrict__ qkv, const int* __restrict__ seg,
                 u16* __restrict__ ob) {
  __shared__ float qs[4][64];
  __shared__ float slds[4][1024];
  __shared__ float pacc[4][4][64];
  __shared__ float redm[4][4];
  __shared__ float reds[4][4];
  __shared__ int sq4[4];

  const int t = threadIdx.x;
  const int wave = t >> 6, lane = t & 63;
  const int bid = blockIdx.x;
  const int qt = bid & 255;
  const int h = (bid >> 8) % NH;
  const int b = (bid >> 8) / NH;
  const int l0 = qt * 4;
  const size_t rowbase = (size_t)b * SEQ;

  {
    const int r = t >> 6, d = t & 63;
    qs[r][d] = bf2f(qkv[(rowbase + l0 + r) * QKVW + h * DHD + d]);
  }
  if (t < 4) sq4[t] = seg[b * SEQ + l0 + t];
  __syncthreads();

  float lg[4][4];
  for (int p = 0; p < 4; p++) {
    const int j = p * 256 + t;
    const u32* kp = (const u32*)(qkv + (rowbase + j) * QKVW + DM + h * DHD);
    float d0 = 0.f, d1 = 0.f, d2 = 0.f, d3 = 0.f;
#pragma unroll 8
    for (int i = 0; i < 32; i++) {
      const u32 kk = kp[i];
      const float ka = bf2f((u16)(kk & 0xffffu));
      const float kb = bf2f((u16)(kk >> 16));
      const float2 q0 = *(const float2*)&qs[0][2 * i];
      const float2 q1 = *(const float2*)&qs[1][2 * i];
      const float2 q2 = *(const float2*)&qs[2][2 * i];
      const float2 q3 = *(const float2*)&qs[3][2 * i];
      d0 += q0.x * ka + q0.y * kb;
      d1 += q1.x * ka + q1.y * kb;
      d2 += q2.x * ka + q2.y * kb;
      d3 += q3.x * ka + q3.y * kb;
    }
    const int sj = seg[b * SEQ + j];
    const float dd[4] = {d0, d1, d2, d3};
#pragma unroll
    for (int r = 0; r < 4; r++) {
      const bool ok = (j <= l0 + r) && (sj == sq4[r]);
      lg[p][r] = ok ? dd[r] : -1e30f;
    }
  }

#pragma unroll
  for (int r = 0; r < 4; r++) {
    float m = fmaxf(fmaxf(lg[0][r], lg[1][r]), fmaxf(lg[2][r], lg[3][r]));
    for (int o = 32; o; o >>= 1) m = fmaxf(m, __shfl_down(m, o, 64));
    if (lane == 0) redm[r][wave] = m;
  }
  __syncthreads();
  float rm[4], ls[4] = {0.f, 0.f, 0.f, 0.f};
#pragma unroll
  for (int r = 0; r < 4; r++)
    rm[r] = fmaxf(fmaxf(redm[r][0], redm[r][1]), fmaxf(redm[r][2], redm[r][3]));
#pragma unroll
  for (int p = 0; p < 4; p++) {
    const int j = p * 256 + t;
#pragma unroll
    for (int r = 0; r < 4; r++) {
      const float e = __expf(lg[p][r] - rm[r]);
      slds[r][j] = e;
      ls[r] += e;
    }
  }
#pragma unroll
  for (int r = 0; r < 4; r++) {
    float s = ls[r];
    for (int o = 32; o; o >>= 1) s += __shfl_down(s, o, 64);
    if (lane == 0) reds[r][wave] = s;
  }
  __syncthreads();
  float rs[4];
#pragma unroll
  for (int r = 0; r < 4; r++) rs[r] = reds[r][0] + reds[r][1] + reds[r][2] + reds[r][3];

  {
    const int d = t & 63, c = t >> 6;
    float a0 = 0.f, a1 = 0.f, a2 = 0.f, a3 = 0.f;
    const int j0 = c * 256;
    for (int j = j0; j < j0 + 256; j++) {
      const float vv = bf2f(qkv[(rowbase + j) * QKVW + 2 * DM + h * DHD + d]);
      a0 += slds[0][j] * vv;
      a1 += slds[1][j] * vv;
      a2 += slds[2][j] * vv;
      a3 += slds[3][j] * vv;
    }
    pacc[c][0][d] = a0; pacc[c][1][d] = a1; pacc[c][2][d] = a2; pacc[c][3][d] = a3;
  }
  __syncthreads();
  {
    const int r = t >> 6, d = t & 63;
    const float o = (pacc[0][r][d] + pacc[1][r][d] + pacc[2][r][d] + pacc[3][r][d]) / rs[r];
    ob[(rowbase + l0 + r) * DM + h * DHD + d] = f2bf(o);
  }
}

static inline void launch_gemm(int epi, const u16* A, const u16* BT, const float* bias,
                               void* out, int M, int N, int K, hipStream_t s) {
  dim3 g((N + 127) / 128, M / 128);
  if (epi == 0)      gemm_bt<0><<<g, 256, 0, s>>>(A, BT, bias, out, M, N, K);
  else if (epi == 1) gemm_bt<1><<<g, 256, 0, s>>>(A, BT, bias, out, M, N, K);
  else               gemm_bt<2><<<g, 256, 0, s>>>(A, BT, bias, out, M, N, K);
}

extern "C" void kernel_launch(void* const* d_in, const int* in_sizes, int n_in,
                              void* d_out, int out_size, void* d_ws, size_t ws_size,
                              hipStream_t stream) {
  (void)in_sizes; (void)n_in; (void)out_size; (void)ws_size;
  const int*   ids  = (const int*)d_in[0];
  const float* tok  = (const float*)d_in[1];
  const float* pos  = (const float*)d_in[2];
  const float* ln1g = (const float*)d_in[3];
  const float* ln1b = (const float*)d_in[4];
  const float* Wq   = (const float*)d_in[5];
  const float* bq   = (const float*)d_in[6];
  const float* Wk   = (const float*)d_in[7];
  const float* bk   = (const float*)d_in[8];
  const float* Wv   = (const float*)d_in[9];
  const float* bv   = (const float*)d_in[10];
  const float* Wo   = (const float*)d_in[11];
  const float* bo   = (const float*)d_in[12];
  const float* ln2g = (const float*)d_in[13];
  const float* ln2b = (const float*)d_in[14];
  const float* W1   = (const float*)d_in[15];
  const float* b1   = (const float*)d_in[16];
  const float* W2   = (const float*)d_in[17];
  const float* b2   = (const float*)d_in[18];

  char* w = (char*)d_ws;
  auto carve = [&](size_t bytes) -> char* {
    char* p = w;
    w += (bytes + 255) & ~(size_t)255;
    return p;
  };
  int*   rel  = (int*)carve((size_t)NTOK * 4);
  int*   seg  = (int*)carve((size_t)NTOK * 4);
  float* x    = (float*)carve((size_t)NTOK * DM * 4);
  u16*   hb   = (u16*)carve((size_t)NTOK * DM * 2);
  u16*   qkvb = (u16*)carve((size_t)NTOK * QKVW * 2);
  u16*   ob   = (u16*)carve((size_t)NTOK * DM * 2);
  u16*   ffb  = (u16*)carve((size_t)NTOK * DFF * 2);
  u16*   Wqkv = (u16*)carve((size_t)QKVW * DM * 2);
  float* bqkv = (float*)carve((size_t)QKVW * 4);
  u16*   WoT  = (u16*)carve((size_t)DM * DM * 2);
  u16*   W1T  = (u16*)carve((size_t)DFF * DM * 2);
  u16*   W2T  = (u16*)carve((size_t)DM * DFF * 2);

  scan_kernel<<<NB, 1024, 0, stream>>>(ids, rel, seg);
  embed_kernel<<<NTOK, 256, 0, stream>>>(ids, rel, tok, pos, x);

  for (int i = 0; i < NLAYERS; i++) {
    ln_kernel<<<NTOK, 256, 0, stream>>>(x, ln1g + (size_t)i * DM, ln1b + (size_t)i * DM, hb);
    repack_qkv<<<(QKVW * DM + 255) / 256, 256, 0, stream>>>(Wq, Wk, Wv, i, Wqkv);
    repack_bias<<<(QKVW + 255) / 256, 256, 0, stream>>>(bq, bk, bv, i, bqkv);
    launch_gemm(0, hb, Wqkv, bqkv, qkvb, NTOK, QKVW, DM, stream);
    attn_kernel<<<NB * NH * (SEQ / 4), 256, 0, stream>>>(qkvb, seg, ob);
    transpose_f2b<<<dim3(DM / 32, DM / 32), 256, 0, stream>>>(Wo + (size_t)i * DM * DM, WoT, DM, DM);
    launch_gemm(1, ob, WoT, bo + (size_t)i * DM, x, NTOK, DM, DM, stream);
    ln_kernel<<<NTOK, 256, 0, stream>>>(x, ln2g + (size_t)i * DM, ln2b + (size_t)i * DM, hb);
    transpose_f2b<<<dim3(DFF / 32, DM / 32), 256, 0, stream>>>(W1 + (size_t)i * DM * DFF, W1T, DM, DFF);
    launch_gemm(2, hb, W1T, b1 + (size_t)i * DFF, ffb, NTOK, DFF, DM, stream);
    transpose_f2b<<<dim3(DM / 32, DFF / 32), 256, 0, stream>>>(W2 + (size_t)i * DFF * DM, W2T, DFF, DM);
    launch_gemm(1, ffb, W2T, b2 + (size_t)i * DM, x, NTOK, DM, DFF, stream);
  }

  f2bf_kernel<<<(NTOK * DM + 255) / 256, 256, 0, stream>>>(x, hb, NTOK * DM);
  gemm_final<<<dim3((NTOK / 128) * ((NV + 127) / 128)), 256, 0, stream>>>(hb, tok, (float*)d_out, NTOK, NV, DM);
}

// Round 2
// 2631.612 us; speedup vs baseline: 1.0484x; 1.0432x over previous
//
#include <hip/hip_runtime.h>

typedef unsigned short u16;
typedef unsigned int u32;
typedef __bf16 bf16x8 __attribute__((ext_vector_type(8)));
typedef float f32x4 __attribute__((ext_vector_type(4)));

#define EOS_ID 50256
#define DM 768
#define NH 12
#define DHD 64
#define SEQ 1024
#define NB 2
#define NLAYERS 4
#define DFF 3072
#define NV 50257
#define NVP 50304   // NV padded to multiple of 128
#define NTOK 2048
#define QKVW 2304

__device__ __forceinline__ float bf2f(u16 u) {
  union { float f; u32 u; } x; x.u = ((u32)u) << 16; return x.f;
}
__device__ __forceinline__ u16 f2bf(float f) {
  union { float f; u32 u; } x; x.f = f;
  u32 u = x.u;
  u += 0x7fffu + ((u >> 16) & 1u);   // round-to-nearest-even
  return (u16)(u >> 16);
}
__device__ __forceinline__ u32 pack2(float a, float b) {
  return (u32)f2bf(a) | ((u32)f2bf(b) << 16);
}

// async global->LDS, 16B per lane; LDS dest is wave-uniform base + lane*16
__device__ __forceinline__ void gload16(const u16* g, u16* l) {
  __builtin_amdgcn_global_load_lds(
      (const __attribute__((address_space(1))) unsigned int*)g,
      (__attribute__((address_space(3))) unsigned int*)l, 16, 0, 0);
}

// ---------- packed-segment scan ----------
__global__ __launch_bounds__(1024)
void scan_kernel(const int* __restrict__ ids, int* __restrict__ rel, int* __restrict__ seg) {
  __shared__ int sm[1024];
  __shared__ int ss[1024];
  const int b = blockIdx.x, t = threadIdx.x;
  const int e = (ids[b * SEQ + t] == EOS_ID) ? 1 : 0;
  sm[t] = e ? t : 0;
  ss[t] = e;
  __syncthreads();
  for (int o = 1; o < 1024; o <<= 1) {
    int vm = 0, vs = 0;
    if (t >= o) { vm = sm[t - o]; vs = ss[t - o]; }
    __syncthreads();
    if (t >= o) { if (vm > sm[t]) sm[t] = vm; ss[t] += vs; }
    __syncthreads();
  }
  rel[b * SEQ + t] = t - sm[t];
  seg[b * SEQ + t] = ss[t];
}

// ---------- embedding: x = tok[id]*sqrt(D) + pos[rel] (fp32 in, fp32 out) ----------
__global__ __launch_bounds__(256)
void embed_kernel(const int* __restrict__ ids, const int* __restrict__ rel,
                  const float* __restrict__ tok, const float* __restrict__ pos,
                  float* __restrict__ x) {
  const int row = blockIdx.x;
  const int id = ids[row];
  const int r = rel[row];
  const float s = 27.712812921102035f;  // sqrt(768)
  for (int d = threadIdx.x; d < DM; d += 256)
    x[(size_t)row * DM + d] = tok[(size_t)id * DM + d] * s + pos[(size_t)r * DM + d];
}

// ---------- tok fp32 [NV][DM] -> bf16 [NVP][DM], pad rows zeroed ----------
__global__ __launch_bounds__(256)
void tok2bf_kernel(const float* __restrict__ tok, u16* __restrict__ out) {
  const size_t i = ((size_t)blockIdx.x * 256 + threadIdx.x) * 8;
  if (i >= (size_t)NVP * DM) return;
  const size_t row = i / DM;
  uint4 o;
  if (row < NV) {
    const float4 f0 = *(const float4*)(tok + i);
    const float4 f1 = *(const float4*)(tok + i + 4);
    o = make_uint4(pack2(f0.x, f0.y), pack2(f0.z, f0.w), pack2(f1.x, f1.y), pack2(f1.z, f1.w));
  } else {
    o = make_uint4(0, 0, 0, 0);
  }
  *(uint4*)(out + i) = o;
}

// ---------- layernorm (fp32 in, fp32 gamma/beta) -> bf16 out ----------
__global__ __launch_bounds__(256)
void ln_kernel(const float* __restrict__ x, const float* __restrict__ g,
               const float* __restrict__ b, u16* __restrict__ out) {
  const int row = blockIdx.x, t = threadIdx.x;
  const int wave = t >> 6, lane = t & 63;
  const float* xr = x + (size_t)row * DM;
  float v0 = xr[t], v1 = xr[t + 256], v2 = xr[t + 512];
  __shared__ float red[4];
  float s = v0 + v1 + v2;
  for (int o = 32; o; o >>= 1) s += __shfl_down(s, o, 64);
  if (lane == 0) red[wave] = s;
  __syncthreads();
  const float mean = (red[0] + red[1] + red[2] + red[3]) * (1.f / DM);
  __syncthreads();
  const float a0 = v0 - mean, a1 = v1 - mean, a2 = v2 - mean;
  float s2 = a0 * a0 + a1 * a1 + a2 * a2;
  for (int o = 32; o; o >>= 1) s2 += __shfl_down(s2, o, 64);
  if (lane == 0) red[wave] = s2;
  __syncthreads();
  const float var = (red[0] + red[1] + red[2] + red[3]) * (1.f / DM);
  const float rstd = rsqrtf(var + 1e-5f);
  u16* orow = out + (size_t)row * DM;
  orow[t]       = f2bf(a0 * rstd * g[t]       + b[t]);
  orow[t + 256] = f2bf(a1 * rstd * g[t + 256] + b[t + 256]);
  orow[t + 512] = f2bf(a2 * rstd * g[t + 512] + b[t + 512]);
}

// ---------- repack Wq/Wk/Wv fp32 [H,D,DH] -> fused bf16 B^T [2304][768] ----------
__global__ __launch_bounds__(256)
void repack_qkv(const float* __restrict__ Wq, const float* __restrict__ Wk,
                const float* __restrict__ Wv, int layer, u16* __restrict__ out) {
  const int idx = blockIdx.x * 256 + threadIdx.x;
  if (idx >= QKVW * DM) return;
  const int n = idx / DM, k = idx % DM;
  const int sel = n / DM;
  const int hh = (n % DM) / DHD, dh = n % DHD;
  const float* W = (sel == 0) ? Wq : (sel == 1) ? Wk : Wv;
  out[idx] = f2bf(W[(((size_t)layer * NH + hh) * DM + k) * DHD + dh]);
}

__global__ __launch_bounds__(256)
void repack_bias(const float* __restrict__ bq, const float* __restrict__ bk,
                 const float* __restrict__ bv, int layer, float* __restrict__ out) {
  const int n = blockIdx.x * 256 + threadIdx.x;
  if (n >= QKVW) return;
  const int sel = n / DM;
  const int hh = (n % DM) / DHD, dh = n % DHD;
  const float* B = (sel == 0) ? bq : (sel == 1) ? bk : bv;
  out[n] = B[((size_t)layer * NH + hh) * DHD + dh];
}

// ---------- transpose fp32 [R][C] -> bf16 [C][R] (R,C multiples of 32) ----------
__global__ __launch_bounds__(256)
void transpose_f2b(const float* __restrict__ src, u16* __restrict__ dst, int R, int C) {
  __shared__ float tile[32][33];
  const int c0 = blockIdx.x * 32, r0 = blockIdx.y * 32;
  const int tx = threadIdx.x & 31, ty = threadIdx.x >> 5;
  for (int i = 0; i < 32; i += 8)
    tile[ty + i][tx] = src[(size_t)(r0 + ty + i) * C + c0 + tx];
  __syncthreads();
  for (int i = 0; i < 32; i += 8)
    dst[(size_t)(c0 + ty + i) * R + r0 + tx] = f2bf(tile[tx][ty + i]);
}

// ---------- fp32 -> bf16 ----------
__global__ __launch_bounds__(256)
void f2bf_kernel(const float* __restrict__ in, u16* __restrict__ out, int n) {
  const int i = blockIdx.x * 256 + threadIdx.x;
  if (i < n) out[i] = f2bf(in[i]);
}

// ---------- GEMM: C[M,N] = A[M,K] @ BT[N,K]^T (bf16 in, fp32 acc, fp32 bias) ----------
// m97 structure: [128][32] linear LDS tiles, global_load_lds width=16, 2 barriers/k-step.
// All callers have M,N multiples of 128 and K multiple of 32 -> no load guards.
// EPI 0: bf16 = acc+bias ; EPI 1: fp32 += acc+bias (residual) ; EPI 2: bf16 gelu(acc+bias)
template <int EPI>
__global__ __launch_bounds__(256)
void gemm_bt(const u16* __restrict__ A, const u16* __restrict__ BT,
             const float* __restrict__ bias, void* __restrict__ out,
             const int M, const int N, const int K) {
  __shared__ u16 As[128 * 32];
  __shared__ u16 Bs[128 * 32];
  const int t = threadIdx.x;
  const int wave = t >> 6, lane = t & 63;
  const int l15 = lane & 15, quad = lane >> 4;
  const int wm = wave >> 1, wn = wave & 1;
  const int m0 = blockIdx.y * 128;
  const int n0 = blockIdx.x * 128;

  const int rsub = lane >> 2;          // 0..15: row within 16-row group
  const int cseg = (lane & 3) * 8;     // u16 col offset (16B per lane)
  const u16* gA0 = A + (size_t)(m0 + wave * 32 + rsub) * K + cseg;
  const u16* gA1 = gA0 + (size_t)16 * K;
  const u16* gB0 = BT + (size_t)(n0 + wave * 32 + rsub) * K + cseg;
  const u16* gB1 = gB0 + (size_t)16 * K;
  u16* lA0 = &As[(wave * 32) * 32];
  u16* lA1 = &As[(wave * 32 + 16) * 32];
  u16* lB0 = &Bs[(wave * 32) * 32];
  u16* lB1 = &Bs[(wave * 32 + 16) * 32];

  f32x4 acc[4][4] = {};

  for (int k0 = 0; k0 < K; k0 += 32) {
    __syncthreads();
    gload16(gA0 + k0, lA0);
    gload16(gA1 + k0, lA1);
    gload16(gB0 + k0, lB0);
    gload16(gB1 + k0, lB1);
    __syncthreads();
    bf16x8 af[4], bfr[4];
#pragma unroll
    for (int mt = 0; mt < 4; mt++)
      af[mt] = *(const bf16x8*)&As[(wm * 64 + mt * 16 + l15) * 32 + quad * 8];
#pragma unroll
    for (int nt = 0; nt < 4; nt++)
      bfr[nt] = *(const bf16x8*)&Bs[(wn * 64 + nt * 16 + l15) * 32 + quad * 8];
#pragma unroll
    for (int mt = 0; mt < 4; mt++)
#pragma unroll
      for (int nt = 0; nt < 4; nt++)
        acc[mt][nt] = __builtin_amdgcn_mfma_f32_16x16x32_bf16(af[mt], bfr[nt], acc[mt][nt], 0, 0, 0);
  }

#pragma unroll
  for (int nt = 0; nt < 4; nt++) {
    const int n = n0 + wn * 64 + nt * 16 + l15;
    const float bvv = bias ? bias[n] : 0.f;
#pragma unroll
    for (int mt = 0; mt < 4; mt++) {
      const int mb = m0 + wm * 64 + mt * 16 + quad * 4;
#pragma unroll
      for (int r = 0; r < 4; r++) {
        const size_t idx = (size_t)(mb + r) * N + n;
        const float v = acc[mt][nt][r] + bvv;
        if (EPI == 0) {
          ((u16*)out)[idx] = f2bf(v);
        } else if (EPI == 1) {
          ((float*)out)[idx] += v;
        } else {
          const float gg = 0.5f * v * (1.f + erff(v * 0.70710678118654752f));
          ((u16*)out)[idx] = f2bf(gg);
        }
      }
    }
  }
}

// ---------- final GEMM: out fp32 [M,NV] = A(bf16)[M,K] @ tokb(bf16)[NVP,K]^T ----------
// XCD-swizzled 1-D grid (M-tile fastest): B-panel fetched into exactly one L2, once.
// m97-style K-loop (global_load_lds); LDS-staged epilogue for full-line 256B stores.
__global__ __launch_bounds__(256)
void gemm_final(const u16* __restrict__ A, const u16* __restrict__ BT,
                float* __restrict__ out, const int M, const int N, const int K) {
  __shared__ float smem_f[4224];       // 16896 B: As|Bs in loop, fp32 scratch in epilogue
  u16* As = (u16*)smem_f;              // 128*32 u16 = 8192 B
  u16* Bs = (u16*)smem_f + 128 * 32;   // 8192 B

  const int t = threadIdx.x;
  const int wave = t >> 6, lane = t & 63;
  const int l15 = lane & 15, quad = lane >> 4;
  const int wm = wave >> 1, wn = wave & 1;

  // XCD swizzle: gridDim.x = 16*393 = 6288, divisible by 8.
  const int bid = blockIdx.x;
  const int nper = gridDim.x >> 3;
  const int gt = (bid & 7) * nper + (bid >> 3);
  const int mtile = gt & 15;
  const int ntile = gt >> 4;
  const int m0 = mtile * 128;
  const int n0 = ntile * 128;

  const int rsub = lane >> 2;
  const int cseg = (lane & 3) * 8;
  const u16* gA0 = A + (size_t)(m0 + wave * 32 + rsub) * K + cseg;
  const u16* gA1 = gA0 + (size_t)16 * K;
  const u16* gB0 = BT + (size_t)(n0 + wave * 32 + rsub) * K + cseg;
  const u16* gB1 = gB0 + (size_t)16 * K;
  u16* lA0 = &As[(wave * 32) * 32];
  u16* lA1 = &As[(wave * 32 + 16) * 32];
  u16* lB0 = &Bs[(wave * 32) * 32];
  u16* lB1 = &Bs[(wave * 32 + 16) * 32];

  f32x4 acc[4][4] = {};

  for (int k0 = 0; k0 < K; k0 += 32) {
    __syncthreads();
    gload16(gA0 + k0, lA0);
    gload16(gA1 + k0, lA1);
    gload16(gB0 + k0, lB0);
    gload16(gB1 + k0, lB1);
    __syncthreads();
    bf16x8 af[4], bfr[4];
#pragma unroll
    for (int mt = 0; mt < 4; mt++)
      af[mt] = *(const bf16x8*)&As[(wm * 64 + mt * 16 + l15) * 32 + quad * 8];
#pragma unroll
    for (int nt = 0; nt < 4; nt++)
      bfr[nt] = *(const bf16x8*)&Bs[(wn * 64 + nt * 16 + l15) * 32 + quad * 8];
#pragma unroll
    for (int mt = 0; mt < 4; mt++)
#pragma unroll
      for (int nt = 0; nt < 4; nt++)
        acc[mt][nt] = __builtin_amdgcn_mfma_f32_16x16x32_bf16(af[mt], bfr[nt], acc[mt][nt], 0, 0, 0);
  }

  // epilogue: stage per-mt slice (32 rows x 128 cols fp32, stride 132) in LDS,
  // then 64 consecutive lanes write 256 B contiguous per store (full L2 lines).
  float* sc = smem_f;  // 32*132*4 = 16896 B
  for (int mt = 0; mt < 4; mt++) {
    __syncthreads();
#pragma unroll
    for (int nt = 0; nt < 4; nt++)
#pragma unroll
      for (int r = 0; r < 4; r++)
        sc[(wm * 16 + quad * 4 + r) * 132 + wn * 64 + nt * 16 + l15] = acc[mt][nt][r];
    __syncthreads();
#pragma unroll
    for (int it = 0; it < 16; it++) {
      const int lin = it * 256 + t;          // 0..4095
      const int s = lin >> 7;                // staged row 0..31
      const int c = lin & 127;               // col within tile
      const int grow = m0 + mt * 16 + (s & 15) + (s >> 4) * 64;
      const int gcol = n0 + c;
      if (gcol < N) out[(size_t)grow * N + gcol] = sc[s * 132 + c];
    }
  }
}

// ---------- attention: 4 query rows / block, scalar fp32, packed-segment mask ----------
__global__ __launch_bounds__(256)
void attn_kernel(const u16* __restrict__ qkv, const int* __restrict__ seg,
                 u16* __restrict__ ob) {
  __shared__ float qs[4][64];
  __shared__ float slds[4][1024];
  __shared__ float pacc[4][4][64];
  __shared__ float redm[4][4];
  __shared__ float reds[4][4];
  __shared__ int sq4[4];

  const int t = threadIdx.x;
  const int wave = t >> 6, lane = t & 63;
  const int bid = blockIdx.x;
  const int qt = bid & 255;
  const int h = (bid >> 8) % NH;
  const int b = (bid >> 8) / NH;
  const int l0 = qt * 4;
  const size_t rowbase = (size_t)b * SEQ;

  {
    const int r = t >> 6, d = t & 63;
    qs[r][d] = bf2f(qkv[(rowbase + l0 + r) * QKVW + h * DHD + d]);
  }
  if (t < 4) sq4[t] = seg[b * SEQ + l0 + t];
  __syncthreads();

  float lg[4][4];
  for (int p = 0; p < 4; p++) {
    const int j = p * 256 + t;
    const u32* kp = (const u32*)(qkv + (rowbase + j) * QKVW + DM + h * DHD);
    float d0 = 0.f, d1 = 0.f, d2 = 0.f, d3 = 0.f;
#pragma unroll 8
    for (int i = 0; i < 32; i++) {
      const u32 kk = kp[i];
      const float ka = bf2f((u16)(kk & 0xffffu));
      const float kb = bf2f((u16)(kk >> 16));
      const float2 q0 = *(const float2*)&qs[0][2 * i];
      const float2 q1 = *(const float2*)&qs[1][2 * i];
      const float2 q2 = *(const float2*)&qs[2][2 * i];
      const float2 q3 = *(const float2*)&qs[3][2 * i];
      d0 += q0.x * ka + q0.y * kb;
      d1 += q1.x * ka + q1.y * kb;
      d2 += q2.x * ka + q2.y * kb;
      d3 += q3.x * ka + q3.y * kb;
    }
    const int sj = seg[b * SEQ + j];
    const float dd[4] = {d0, d1, d2, d3};
#pragma unroll
    for (int r = 0; r < 4; r++) {
      const bool ok = (j <= l0 + r) && (sj == sq4[r]);
      lg[p][r] = ok ? dd[r] : -1e30f;
    }
  }

#pragma unroll
  for (int r = 0; r < 4; r++) {
    float m = fmaxf(fmaxf(lg[0][r], lg[1][r]), fmaxf(lg[2][r], lg[3][r]));
    for (int o = 32; o; o >>= 1) m = fmaxf(m, __shfl_down(m, o, 64));
    if (lane == 0) redm[r][wave] = m;
  }
  __syncthreads();
  float rm[4], ls[4] = {0.f, 0.f, 0.f, 0.f};
#pragma unroll
  for (int r = 0; r < 4; r++)
    rm[r] = fmaxf(fmaxf(redm[r][0], redm[r][1]), fmaxf(redm[r][2], redm[r][3]));
#pragma unroll
  for (int p = 0; p < 4; p++) {
    const int j = p * 256 + t;
#pragma unroll
    for (int r = 0; r < 4; r++) {
      const float e = __expf(lg[p][r] - rm[r]);
      slds[r][j] = e;
      ls[r] += e;
    }
  }
#pragma unroll
  for (int r = 0; r < 4; r++) {
    float s = ls[r];
    for (int o = 32; o; o >>= 1) s += __shfl_down(s, o, 64);
    if (lane == 0) reds[r][wave] = s;
  }
  __syncthreads();
  float rs[4];
#pragma unroll
  for (int r = 0; r < 4; r++) rs[r] = reds[r][0] + reds[r][1] + reds[r][2] + reds[r][3];

  {
    const int d = t & 63, c = t >> 6;
    float a0 = 0.f, a1 = 0.f, a2 = 0.f, a3 = 0.f;
    const int j0 = c * 256;
    for (int j = j0; j < j0 + 256; j++) {
      const float vv = bf2f(qkv[(rowbase + j) * QKVW + 2 * DM + h * DHD + d]);
      a0 += slds[0][j] * vv;
      a1 += slds[1][j] * vv;
      a2 += slds[2][j] * vv;
      a3 += slds[3][j] * vv;
    }
    pacc[c][0][d] = a0; pacc[c][1][d] = a1; pacc[c][2][d] = a2; pacc[c][3][d] = a3;
  }
  __syncthreads();
  {
    const int r = t >> 6, d = t & 63;
    const float o = (pacc[0][r][d] + pacc[1][r][d] + pacc[2][r][d] + pacc[3][r][d]) / rs[r];
    ob[(rowbase + l0 + r) * DM + h * DHD + d] = f2bf(o);
  }
}

static inline void launch_gemm(int epi, const u16* A, const u16* BT, const float* bias,
                               void* out, int M, int N, int K, hipStream_t s) {
  dim3 g(N / 128, M / 128);
  if (epi == 0)      gemm_bt<0><<<g, 256, 0, s>>>(A, BT, bias, out, M, N, K);
  else if (epi == 1) gemm_bt<1><<<g, 256, 0, s>>>(A, BT, bias, out, M, N, K);
  else               gemm_bt<2><<<g, 256, 0, s>>>(A, BT, bias, out, M, N, K);
}

extern "C" void kernel_launch(void* const* d_in, const int* in_sizes, int n_in,
                              void* d_out, int out_size, void* d_ws, size_t ws_size,
                              hipStream_t stream) {
  (void)in_sizes; (void)n_in; (void)out_size; (void)ws_size;
  const int*   ids  = (const int*)d_in[0];
  const float* tok  = (const float*)d_in[1];
  const float* pos  = (const float*)d_in[2];
  const float* ln1g = (const float*)d_in[3];
  const float* ln1b = (const float*)d_in[4];
  const float* Wq   = (const float*)d_in[5];
  const float* bq   = (const float*)d_in[6];
  const float* Wk   = (const float*)d_in[7];
  const float* bk   = (const float*)d_in[8];
  const float* Wv   = (const float*)d_in[9];
  const float* bv   = (const float*)d_in[10];
  const float* Wo   = (const float*)d_in[11];
  const float* bo   = (const float*)d_in[12];
  const float* ln2g = (const float*)d_in[13];
  const float* ln2b = (const float*)d_in[14];
  const float* W1   = (const float*)d_in[15];
  const float* b1   = (const float*)d_in[16];
  const float* W2   = (const float*)d_in[17];
  const float* b2   = (const float*)d_in[18];

  char* w = (char*)d_ws;
  auto carve = [&](size_t bytes) -> char* {
    char* p = w;
    w += (bytes + 255) & ~(size_t)255;
    return p;
  };
  int*   rel  = (int*)carve((size_t)NTOK * 4);
  int*   seg  = (int*)carve((size_t)NTOK * 4);
  float* x    = (float*)carve((size_t)NTOK * DM * 4);
  u16*   hb   = (u16*)carve((size_t)NTOK * DM * 2);
  u16*   qkvb = (u16*)carve((size_t)NTOK * QKVW * 2);
  u16*   ob   = (u16*)carve((size_t)NTOK * DM * 2);
  u16*   ffb  = (u16*)carve((size_t)NTOK * DFF * 2);
  u16*   Wqkv = (u16*)carve((size_t)QKVW * DM * 2);
  float* bqkv = (float*)carve((size_t)QKVW * 4);
  u16*   WoT  = (u16*)carve((size_t)DM * DM * 2);
  u16*   W1T  = (u16*)carve((size_t)DFF * DM * 2);
  u16*   W2T  = (u16*)carve((size_t)DM * DFF * 2);
  u16*   tokb = (u16*)carve((size_t)NVP * DM * 2);   // 77.3 MB padded bf16 decoder

  scan_kernel<<<NB, 1024, 0, stream>>>(ids, rel, seg);
  embed_kernel<<<NTOK, 256, 0, stream>>>(ids, rel, tok, pos, x);
  tok2bf_kernel<<<(int)(((size_t)NVP * DM / 8 + 255) / 256), 256, 0, stream>>>(tok, tokb);

  for (int i = 0; i < NLAYERS; i++) {
    ln_kernel<<<NTOK, 256, 0, stream>>>(x, ln1g + (size_t)i * DM, ln1b + (size_t)i * DM, hb);
    repack_qkv<<<(QKVW * DM + 255) / 256, 256, 0, stream>>>(Wq, Wk, Wv, i, Wqkv);
    repack_bias<<<(QKVW + 255) / 256, 256, 0, stream>>>(bq, bk, bv, i, bqkv);
    launch_gemm(0, hb, Wqkv, bqkv, qkvb, NTOK, QKVW, DM, stream);
    attn_kernel<<<NB * NH * (SEQ / 4), 256, 0, stream>>>(qkvb, seg, ob);
    transpose_f2b<<<dim3(DM / 32, DM / 32), 256, 0, stream>>>(Wo + (size_t)i * DM * DM, WoT, DM, DM);
    launch_gemm(1, ob, WoT, bo + (size_t)i * DM, x, NTOK, DM, DM, stream);
    ln_kernel<<<NTOK, 256, 0, stream>>>(x, ln2g + (size_t)i * DM, ln2b + (size_t)i * DM, hb);
    transpose_f2b<<<dim3(DFF / 32, DM / 32), 256, 0, stream>>>(W1 + (size_t)i * DM * DFF, W1T, DM, DFF);
    launch_gemm(2, hb, W1T, b1 + (size_t)i * DFF, ffb, NTOK, DFF, DM, stream);
    transpose_f2b<<<dim3(DM / 32, DFF / 32), 256, 0, stream>>>(W2 + (size_t)i * DFF * DM, W2T, DFF, DM);
    launch_gemm(1, ffb, W2T, b2 + (size_t)i * DM, x, NTOK, DM, DFF, stream);
  }

  f2bf_kernel<<<(NTOK * DM + 255) / 256, 256, 0, stream>>>(x, hb, NTOK * DM);
  gemm_final<<<dim3((NTOK / 128) * (NVP / 128)), 256, 0, stream>>>(hb, tokb, (float*)d_out, NTOK, NV, DM);
}

// Round 3
// 1827.347 us; speedup vs baseline: 1.5099x; 1.4401x over previous
//
#include <hip/hip_runtime.h>

typedef unsigned short u16;
typedef unsigned int u32;
typedef __bf16 bf16x8 __attribute__((ext_vector_type(8)));
typedef float f32x4 __attribute__((ext_vector_type(4)));

#define EOS_ID 50256
#define DM 768
#define NH 12
#define DHD 64
#define SEQ 1024
#define NB 2
#define NLAYERS 4
#define DFF 3072
#define NV 50257
#define NVP 50304   // NV padded to multiple of 128
#define NTOK 2048
#define QKVW 2304

__device__ __forceinline__ float bf2f(u16 u) {
  union { float f; u32 u; } x; x.u = ((u32)u) << 16; return x.f;
}
__device__ __forceinline__ u16 f2bf(float f) {
  union { float f; u32 u; } x; x.f = f;
  u32 u = x.u;
  u += 0x7fffu + ((u >> 16) & 1u);   // round-to-nearest-even
  return (u16)(u >> 16);
}
__device__ __forceinline__ u32 pack2(float a, float b) {
  return (u32)f2bf(a) | ((u32)f2bf(b) << 16);
}

// async global->LDS, 16B per lane; LDS dest is wave-uniform base + lane*16
__device__ __forceinline__ void gload16(const u16* g, u16* l) {
  __builtin_amdgcn_global_load_lds(
      (const __attribute__((address_space(1))) unsigned int*)g,
      (__attribute__((address_space(3))) unsigned int*)l, 16, 0, 0);
}

// ---------- packed-segment scan ----------
__global__ __launch_bounds__(1024)
void scan_kernel(const int* __restrict__ ids, int* __restrict__ rel, int* __restrict__ seg) {
  __shared__ int sm[1024];
  __shared__ int ss[1024];
  const int b = blockIdx.x, t = threadIdx.x;
  const int e = (ids[b * SEQ + t] == EOS_ID) ? 1 : 0;
  sm[t] = e ? t : 0;
  ss[t] = e;
  __syncthreads();
  for (int o = 1; o < 1024; o <<= 1) {
    int vm = 0, vs = 0;
    if (t >= o) { vm = sm[t - o]; vs = ss[t - o]; }
    __syncthreads();
    if (t >= o) { if (vm > sm[t]) sm[t] = vm; ss[t] += vs; }
    __syncthreads();
  }
  rel[b * SEQ + t] = t - sm[t];
  seg[b * SEQ + t] = ss[t];
}

// ---------- embedding: x = tok[id]*sqrt(D) + pos[rel] (fp32 in, fp32 out) ----------
__global__ __launch_bounds__(256)
void embed_kernel(const int* __restrict__ ids, const int* __restrict__ rel,
                  const float* __restrict__ tok, const float* __restrict__ pos,
                  float* __restrict__ x) {
  const int row = blockIdx.x;
  const int id = ids[row];
  const int r = rel[row];
  const float s = 27.712812921102035f;  // sqrt(768)
  for (int d = threadIdx.x; d < DM; d += 256)
    x[(size_t)row * DM + d] = tok[(size_t)id * DM + d] * s + pos[(size_t)r * DM + d];
}

// ---------- tok fp32 [NV][DM] -> bf16 [NVP][DM], pad rows zeroed ----------
__global__ __launch_bounds__(256)
void tok2bf_kernel(const float* __restrict__ tok, u16* __restrict__ out) {
  const size_t i = ((size_t)blockIdx.x * 256 + threadIdx.x) * 8;
  if (i >= (size_t)NVP * DM) return;
  const size_t row = i / DM;
  uint4 o;
  if (row < NV) {
    const float4 f0 = *(const float4*)(tok + i);
    const float4 f1 = *(const float4*)(tok + i + 4);
    o = make_uint4(pack2(f0.x, f0.y), pack2(f0.z, f0.w), pack2(f1.x, f1.y), pack2(f1.z, f1.w));
  } else {
    o = make_uint4(0, 0, 0, 0);
  }
  *(uint4*)(out + i) = o;
}

// ---------- layernorm (fp32 in, fp32 gamma/beta) -> bf16 out ----------
__global__ __launch_bounds__(256)
void ln_kernel(const float* __restrict__ x, const float* __restrict__ g,
               const float* __restrict__ b, u16* __restrict__ out) {
  const int row = blockIdx.x, t = threadIdx.x;
  const int wave = t >> 6, lane = t & 63;
  const float* xr = x + (size_t)row * DM;
  float v0 = xr[t], v1 = xr[t + 256], v2 = xr[t + 512];
  __shared__ float red[4];
  float s = v0 + v1 + v2;
  for (int o = 32; o; o >>= 1) s += __shfl_down(s, o, 64);
  if (lane == 0) red[wave] = s;
  __syncthreads();
  const float mean = (red[0] + red[1] + red[2] + red[3]) * (1.f / DM);
  __syncthreads();
  const float a0 = v0 - mean, a1 = v1 - mean, a2 = v2 - mean;
  float s2 = a0 * a0 + a1 * a1 + a2 * a2;
  for (int o = 32; o; o >>= 1) s2 += __shfl_down(s2, o, 64);
  if (lane == 0) red[wave] = s2;
  __syncthreads();
  const float var = (red[0] + red[1] + red[2] + red[3]) * (1.f / DM);
  const float rstd = rsqrtf(var + 1e-5f);
  u16* orow = out + (size_t)row * DM;
  orow[t]       = f2bf(a0 * rstd * g[t]       + b[t]);
  orow[t + 256] = f2bf(a1 * rstd * g[t + 256] + b[t + 256]);
  orow[t + 512] = f2bf(a2 * rstd * g[t + 512] + b[t + 512]);
}

// ---------- repack Wq/Wk/Wv fp32 [H,D,DH] -> fused bf16 B^T [2304][768] ----------
__global__ __launch_bounds__(256)
void repack_qkv(const float* __restrict__ Wq, const float* __restrict__ Wk,
                const float* __restrict__ Wv, int layer, u16* __restrict__ out) {
  const int idx = blockIdx.x * 256 + threadIdx.x;
  if (idx >= QKVW * DM) return;
  const int n = idx / DM, k = idx % DM;
  const int sel = n / DM;
  const int hh = (n % DM) / DHD, dh = n % DHD;
  const float* W = (sel == 0) ? Wq : (sel == 1) ? Wk : Wv;
  out[idx] = f2bf(W[(((size_t)layer * NH + hh) * DM + k) * DHD + dh]);
}

__global__ __launch_bounds__(256)
void repack_bias(const float* __restrict__ bq, const float* __restrict__ bk,
                 const float* __restrict__ bv, int layer, float* __restrict__ out) {
  const int n = blockIdx.x * 256 + threadIdx.x;
  if (n >= QKVW) return;
  const int sel = n / DM;
  const int hh = (n % DM) / DHD, dh = n % DHD;
  const float* B = (sel == 0) ? bq : (sel == 1) ? bk : bv;
  out[n] = B[((size_t)layer * NH + hh) * DHD + dh];
}

// ---------- transpose fp32 [R][C] -> bf16 [C][R] (R,C multiples of 32) ----------
__global__ __launch_bounds__(256)
void transpose_f2b(const float* __restrict__ src, u16* __restrict__ dst, int R, int C) {
  __shared__ float tile[32][33];
  const int c0 = blockIdx.x * 32, r0 = blockIdx.y * 32;
  const int tx = threadIdx.x & 31, ty = threadIdx.x >> 5;
  for (int i = 0; i < 32; i += 8)
    tile[ty + i][tx] = src[(size_t)(r0 + ty + i) * C + c0 + tx];
  __syncthreads();
  for (int i = 0; i < 32; i += 8)
    dst[(size_t)(c0 + ty + i) * R + r0 + tx] = f2bf(tile[tx][ty + i]);
}

// ---------- fp32 -> bf16 ----------
__global__ __launch_bounds__(256)
void f2bf_kernel(const float* __restrict__ in, u16* __restrict__ out, int n) {
  const int i = blockIdx.x * 256 + threadIdx.x;
  if (i < n) out[i] = f2bf(in[i]);
}

// ---------- GEMM: C[M,N] = A[M,K] @ BT[N,K]^T (bf16 in, fp32 acc, fp32 bias) ----------
// m97 structure: [128][32] linear LDS tiles, global_load_lds width=16, 2 barriers/k-step.
// All callers have M,N multiples of 128 and K multiple of 32 -> no load guards.
// EPI 0: bf16 = acc+bias ; EPI 1: fp32 += acc+bias (residual) ; EPI 2: bf16 gelu(acc+bias)
template <int EPI>
__global__ __launch_bounds__(256)
void gemm_bt(const u16* __restrict__ A, const u16* __restrict__ BT,
             const float* __restrict__ bias, void* __restrict__ out,
             const int M, const int N, const int K) {
  __shared__ u16 As[128 * 32];
  __shared__ u16 Bs[128 * 32];
  const int t = threadIdx.x;
  const int wave = t >> 6, lane = t & 63;
  const int l15 = lane & 15, quad = lane >> 4;
  const int wm = wave >> 1, wn = wave & 1;
  const int m0 = blockIdx.y * 128;
  const int n0 = blockIdx.x * 128;

  const int rsub = lane >> 2;          // 0..15: row within 16-row group
  const int cseg = (lane & 3) * 8;     // u16 col offset (16B per lane)
  const u16* gA0 = A + (size_t)(m0 + wave * 32 + rsub) * K + cseg;
  const u16* gA1 = gA0 + (size_t)16 * K;
  const u16* gB0 = BT + (size_t)(n0 + wave * 32 + rsub) * K + cseg;
  const u16* gB1 = gB0 + (size_t)16 * K;
  u16* lA0 = &As[(wave * 32) * 32];
  u16* lA1 = &As[(wave * 32 + 16) * 32];
  u16* lB0 = &Bs[(wave * 32) * 32];
  u16* lB1 = &Bs[(wave * 32 + 16) * 32];

  f32x4 acc[4][4] = {};

  for (int k0 = 0; k0 < K; k0 += 32) {
    __syncthreads();
    gload16(gA0 + k0, lA0);
    gload16(gA1 + k0, lA1);
    gload16(gB0 + k0, lB0);
    gload16(gB1 + k0, lB1);
    __syncthreads();
    bf16x8 af[4], bfr[4];
#pragma unroll
    for (int mt = 0; mt < 4; mt++)
      af[mt] = *(const bf16x8*)&As[(wm * 64 + mt * 16 + l15) * 32 + quad * 8];
#pragma unroll
    for (int nt = 0; nt < 4; nt++)
      bfr[nt] = *(const bf16x8*)&Bs[(wn * 64 + nt * 16 + l15) * 32 + quad * 8];
#pragma unroll
    for (int mt = 0; mt < 4; mt++)
#pragma unroll
      for (int nt = 0; nt < 4; nt++)
        acc[mt][nt] = __builtin_amdgcn_mfma_f32_16x16x32_bf16(af[mt], bfr[nt], acc[mt][nt], 0, 0, 0);
  }

#pragma unroll
  for (int nt = 0; nt < 4; nt++) {
    const int n = n0 + wn * 64 + nt * 16 + l15;
    const float bvv = bias ? bias[n] : 0.f;
#pragma unroll
    for (int mt = 0; mt < 4; mt++) {
      const int mb = m0 + wm * 64 + mt * 16 + quad * 4;
#pragma unroll
      for (int r = 0; r < 4; r++) {
        const size_t idx = (size_t)(mb + r) * N + n;
        const float v = acc[mt][nt][r] + bvv;
        if (EPI == 0) {
          ((u16*)out)[idx] = f2bf(v);
        } else if (EPI == 1) {
          ((float*)out)[idx] += v;
        } else {
          const float gg = 0.5f * v * (1.f + erff(v * 0.70710678118654752f));
          ((u16*)out)[idx] = f2bf(gg);
        }
      }
    }
  }
}

// ---------- final GEMM: out fp32 [M,NV] = A(bf16)[M,K] @ tokb(bf16)[NVP,K]^T ----------
// XCD-swizzled 1-D grid (M-tile fastest): B-panel fetched into exactly one L2, once.
// m97-style K-loop (global_load_lds); LDS-staged epilogue for full-line 256B stores.
__global__ __launch_bounds__(256)
void gemm_final(const u16* __restrict__ A, const u16* __restrict__ BT,
                float* __restrict__ out, const int M, const int N, const int K) {
  __shared__ float smem_f[4224];       // 16896 B: As|Bs in loop, fp32 scratch in epilogue
  u16* As = (u16*)smem_f;              // 128*32 u16 = 8192 B
  u16* Bs = (u16*)smem_f + 128 * 32;   // 8192 B

  const int t = threadIdx.x;
  const int wave = t >> 6, lane = t & 63;
  const int l15 = lane & 15, quad = lane >> 4;
  const int wm = wave >> 1, wn = wave & 1;

  // XCD swizzle: gridDim.x = 16*393 = 6288, divisible by 8.
  const int bid = blockIdx.x;
  const int nper = gridDim.x >> 3;
  const int gt = (bid & 7) * nper + (bid >> 3);
  const int mtile = gt & 15;
  const int ntile = gt >> 4;
  const int m0 = mtile * 128;
  const int n0 = ntile * 128;

  const int rsub = lane >> 2;
  const int cseg = (lane & 3) * 8;
  const u16* gA0 = A + (size_t)(m0 + wave * 32 + rsub) * K + cseg;
  const u16* gA1 = gA0 + (size_t)16 * K;
  const u16* gB0 = BT + (size_t)(n0 + wave * 32 + rsub) * K + cseg;
  const u16* gB1 = gB0 + (size_t)16 * K;
  u16* lA0 = &As[(wave * 32) * 32];
  u16* lA1 = &As[(wave * 32 + 16) * 32];
  u16* lB0 = &Bs[(wave * 32) * 32];
  u16* lB1 = &Bs[(wave * 32 + 16) * 32];

  f32x4 acc[4][4] = {};

  for (int k0 = 0; k0 < K; k0 += 32) {
    __syncthreads();
    gload16(gA0 + k0, lA0);
    gload16(gA1 + k0, lA1);
    gload16(gB0 + k0, lB0);
    gload16(gB1 + k0, lB1);
    __syncthreads();
    bf16x8 af[4], bfr[4];
#pragma unroll
    for (int mt = 0; mt < 4; mt++)
      af[mt] = *(const bf16x8*)&As[(wm * 64 + mt * 16 + l15) * 32 + quad * 8];
#pragma unroll
    for (int nt = 0; nt < 4; nt++)
      bfr[nt] = *(const bf16x8*)&Bs[(wn * 64 + nt * 16 + l15) * 32 + quad * 8];
#pragma unroll
    for (int mt = 0; mt < 4; mt++)
#pragma unroll
      for (int nt = 0; nt < 4; nt++)
        acc[mt][nt] = __builtin_amdgcn_mfma_f32_16x16x32_bf16(af[mt], bfr[nt], acc[mt][nt], 0, 0, 0);
  }

  // epilogue: stage per-mt slice (32 rows x 128 cols fp32, stride 132) in LDS,
  // then 64 consecutive lanes write 256 B contiguous per store (full L2 lines).
  float* sc = smem_f;  // 32*132*4 = 16896 B
  for (int mt = 0; mt < 4; mt++) {
    __syncthreads();
#pragma unroll
    for (int nt = 0; nt < 4; nt++)
#pragma unroll
      for (int r = 0; r < 4; r++)
        sc[(wm * 16 + quad * 4 + r) * 132 + wn * 64 + nt * 16 + l15] = acc[mt][nt][r];
    __syncthreads();
#pragma unroll
    for (int it = 0; it < 16; it++) {
      const int lin = it * 256 + t;          // 0..4095
      const int s = lin >> 7;                // staged row 0..31
      const int c = lin & 127;               // col within tile
      const int grow = m0 + mt * 16 + (s & 15) + (s >> 4) * 64;
      const int gcol = n0 + c;
      if (gcol < N) out[(size_t)grow * N + gcol] = sc[s * 132 + c];
    }
  }
}

// ---------- MFMA flash attention ----------
// Block = (b, h, 64 q-rows); 4 waves x 16 q-rows; KV chunks of 32.
// Swapped QK^T: S^T[kv][q] = mfma(K_frag, Q_frag) -> softmax state lane-local at q=l15.
// PV as O^T = V^T @ P: C[d][q=l15] keeps rescale per-lane. V^T and P staged in LDS
// (stride 40 u16: 16B-aligned b128 reads, ~2-way banks). K/V prefetched 1 chunk ahead.
__global__ __launch_bounds__(256)
void attn_kernel(const u16* __restrict__ qkv, const int* __restrict__ seg,
                 u16* __restrict__ ob) {
  __shared__ int seg_lds[SEQ];
  __shared__ u16 VT[64 * 40];       // V^T tile [d][kv], row stride 40 u16
  __shared__ u16 PL[4][16 * 40];    // per-wave P [q][kv], row stride 40 u16

  const int t = threadIdx.x;
  const int wave = t >> 6, lane = t & 63;
  const int l15 = lane & 15, quad = lane >> 4;
  const int bid = blockIdx.x;
  const int qb = bid & 15;
  const int hh = (bid >> 4) % NH;
  const int b = (bid >> 4) / NH;
  const size_t rowbase = (size_t)b * SEQ;
  const int kvmax = (qb + 1) * 64;
  const int qw0 = qb * 64 + wave * 16;   // wave's first q row

  for (int idx = t; idx < kvmax; idx += 256) seg_lds[idx] = seg[b * SEQ + idx];

  // Q fragments: lane holds Q[qw0+l15][d = half*32 + quad*8 .. +7]
  const u16* qrow = qkv + (rowbase + qw0 + l15) * QKVW + hh * DHD;
  const bf16x8 qf0 = *(const bf16x8*)(qrow + quad * 8);
  const bf16x8 qf1 = *(const bf16x8*)(qrow + 32 + quad * 8);

  __syncthreads();
  const int si = seg_lds[qw0 + l15];

  const int vkv = t >> 3;          // 0..31 (kv row within chunk)
  const int vdd = (t & 7) * 8;     // d offset, 16B per thread
  const u16* vbase = qkv + rowbase * QKVW + 2 * DM + hh * DHD + vdd;
  const u16* kbase = qkv + rowbase * QKVW + DM + hh * DHD;

  // prefetch chunk 0
  uint4 vld = *(const uint4*)(vbase + (size_t)vkv * QKVW);
  uint4 kfa = *(const uint4*)(kbase + (size_t)l15 * QKVW + quad * 8);
  uint4 kfb = *(const uint4*)(kbase + (size_t)l15 * QKVW + 32 + quad * 8);
  uint4 kfc = *(const uint4*)(kbase + (size_t)(16 + l15) * QKVW + quad * 8);
  uint4 kfd = *(const uint4*)(kbase + (size_t)(16 + l15) * QKVW + 32 + quad * 8);

  f32x4 o0 = {}, o1 = {}, o2 = {}, o3 = {};
  float mrun = -1e30f, lrun = 0.f;

  const int nch = kvmax >> 5;
  for (int c = 0; c < nch; c++) {
    const int j0 = c << 5;
    __syncthreads();               // prev chunk's VT reads complete
    {
      const u16* pv = (const u16*)&vld;
#pragma unroll
      for (int jj = 0; jj < 8; jj++) VT[(vdd + jj) * 40 + vkv] = pv[jj];
    }
    __syncthreads();               // VT ready
    // prefetch next chunk (last iter re-loads current; harmless)
    const int j1 = (c + 1 < nch) ? j0 + 32 : j0;
    uint4 vld_n = *(const uint4*)(vbase + (size_t)(j1 + vkv) * QKVW);
    uint4 kfa_n = *(const uint4*)(kbase + (size_t)(j1 + l15) * QKVW + quad * 8);
    uint4 kfb_n = *(const uint4*)(kbase + (size_t)(j1 + l15) * QKVW + 32 + quad * 8);
    uint4 kfc_n = *(const uint4*)(kbase + (size_t)(j1 + 16 + l15) * QKVW + quad * 8);
    uint4 kfd_n = *(const uint4*)(kbase + (size_t)(j1 + 16 + l15) * QKVW + 32 + quad * 8);

    // S^T tiles: S^T[kv = quad*4+r (+16)][q = l15], accumulate over d halves
    f32x4 s0 = {}, s1 = {};
    s0 = __builtin_amdgcn_mfma_f32_16x16x32_bf16(*(const bf16x8*)&kfa, qf0, s0, 0, 0, 0);
    s0 = __builtin_amdgcn_mfma_f32_16x16x32_bf16(*(const bf16x8*)&kfb, qf1, s0, 0, 0, 0);
    s1 = __builtin_amdgcn_mfma_f32_16x16x32_bf16(*(const bf16x8*)&kfc, qf0, s1, 0, 0, 0);
    s1 = __builtin_amdgcn_mfma_f32_16x16x32_bf16(*(const bf16x8*)&kfd, qf1, s1, 0, 0, 0);

    const int iq = qw0 + l15;
    float p[8];
    float cmax = -1e30f;
#pragma unroll
    for (int r = 0; r < 4; r++) {
      int j = j0 + quad * 4 + r;
      bool ok = (j <= iq) && (seg_lds[j] == si);
      float sv = ok ? s0[r] : -1e30f;
      p[r] = sv; cmax = fmaxf(cmax, sv);
      j += 16;
      ok = (j <= iq) && (seg_lds[j] == si);
      sv = ok ? s1[r] : -1e30f;
      p[4 + r] = sv; cmax = fmaxf(cmax, sv);
    }
    // reduce over the 4 quad-replicas of each q (lanes l15, +16, +32, +48)
    cmax = fmaxf(cmax, __shfl_xor(cmax, 16, 64));
    cmax = fmaxf(cmax, __shfl_xor(cmax, 32, 64));
    const float mnew = fmaxf(mrun, cmax);
    const float fsc = __expf(mrun - mnew);   // <= 1 always; exp(0)=1 if unchanged
    mrun = mnew;
    float csum = 0.f;
#pragma unroll
    for (int r = 0; r < 8; r++) {
      const float e = (p[r] > -5e29f) ? __expf(p[r] - mnew) : 0.f;  // masked -> exactly 0
      p[r] = e; csum += e;
    }
    csum += __shfl_xor(csum, 16, 64);
    csum += __shfl_xor(csum, 32, 64);
    lrun = lrun * fsc + csum;
#pragma unroll
    for (int r = 0; r < 4; r++) { o0[r] *= fsc; o1[r] *= fsc; o2[r] *= fsc; o3[r] *= fsc; }

    // bounce P through wave-private LDS: [q=l15][kv] layout, kv contiguous
    u32* plw = (u32*)&PL[wave][l15 * 40 + quad * 4];
    plw[0] = pack2(p[0], p[1]);
    plw[1] = pack2(p[2], p[3]);
    u32* plw2 = (u32*)&PL[wave][l15 * 40 + 16 + quad * 4];
    plw2[0] = pack2(p[4], p[5]);
    plw2[1] = pack2(p[6], p[7]);

    // fragments: P^T rows (q=l15) and V^T rows (d), k = kv = quad*8..+7
    const bf16x8 pf = *(const bf16x8*)&PL[wave][l15 * 40 + quad * 8];
    const bf16x8 va = *(const bf16x8*)&VT[(l15) * 40 + quad * 8];
    const bf16x8 vb = *(const bf16x8*)&VT[(16 + l15) * 40 + quad * 8];
    const bf16x8 vc = *(const bf16x8*)&VT[(32 + l15) * 40 + quad * 8];
    const bf16x8 vd8 = *(const bf16x8*)&VT[(48 + l15) * 40 + quad * 8];
    o0 = __builtin_amdgcn_mfma_f32_16x16x32_bf16(va, pf, o0, 0, 0, 0);
    o1 = __builtin_amdgcn_mfma_f32_16x16x32_bf16(vb, pf, o1, 0, 0, 0);
    o2 = __builtin_amdgcn_mfma_f32_16x16x32_bf16(vc, pf, o2, 0, 0, 0);
    o3 = __builtin_amdgcn_mfma_f32_16x16x32_bf16(vd8, pf, o3, 0, 0, 0);

    vld = vld_n; kfa = kfa_n; kfb = kfb_n; kfc = kfc_n; kfd = kfd_n;
  }

  // O^T layout: o_mt[r] = O[q = qw0+l15][d = mt*16 + quad*4 + r]
  const float inv = 1.f / lrun;
  u16* orow = ob + (rowbase + qw0 + l15) * DM + hh * DHD;
#pragma unroll
  for (int r = 0; r < 4; r++) {
    orow[quad * 4 + r]      = f2bf(o0[r] * inv);
    orow[16 + quad * 4 + r] = f2bf(o1[r] * inv);
    orow[32 + quad * 4 + r] = f2bf(o2[r] * inv);
    orow[48 + quad * 4 + r] = f2bf(o3[r] * inv);
  }
}

static inline void launch_gemm(int epi, const u16* A, const u16* BT, const float* bias,
                               void* out, int M, int N, int K, hipStream_t s) {
  dim3 g(N / 128, M / 128);
  if (epi == 0)      gemm_bt<0><<<g, 256, 0, s>>>(A, BT, bias, out, M, N, K);
  else if (epi == 1) gemm_bt<1><<<g, 256, 0, s>>>(A, BT, bias, out, M, N, K);
  else               gemm_bt<2><<<g, 256, 0, s>>>(A, BT, bias, out, M, N, K);
}

extern "C" void kernel_launch(void* const* d_in, const int* in_sizes, int n_in,
                              void* d_out, int out_size, void* d_ws, size_t ws_size,
                              hipStream_t stream) {
  (void)in_sizes; (void)n_in; (void)out_size; (void)ws_size;
  const int*   ids  = (const int*)d_in[0];
  const float* tok  = (const float*)d_in[1];
  const float* pos  = (const float*)d_in[2];
  const float* ln1g = (const float*)d_in[3];
  const float* ln1b = (const float*)d_in[4];
  const float* Wq   = (const float*)d_in[5];
  const float* bq   = (const float*)d_in[6];
  const float* Wk   = (const float*)d_in[7];
  const float* bk   = (const float*)d_in[8];
  const float* Wv   = (const float*)d_in[9];
  const float* bv   = (const float*)d_in[10];
  const float* Wo   = (const float*)d_in[11];
  const float* bo   = (const float*)d_in[12];
  const float* ln2g = (const float*)d_in[13];
  const float* ln2b = (const float*)d_in[14];
  const float* W1   = (const float*)d_in[15];
  const float* b1   = (const float*)d_in[16];
  const float* W2   = (const float*)d_in[17];
  const float* b2   = (const float*)d_in[18];

  char* w = (char*)d_ws;
  auto carve = [&](size_t bytes) -> char* {
    char* p = w;
    w += (bytes + 255) & ~(size_t)255;
    return p;
  };
  int*   rel  = (int*)carve((size_t)NTOK * 4);
  int*   seg  = (int*)carve((size_t)NTOK * 4);
  float* x    = (float*)carve((size_t)NTOK * DM * 4);
  u16*   hb   = (u16*)carve((size_t)NTOK * DM * 2);
  u16*   qkvb = (u16*)carve((size_t)NTOK * QKVW * 2);
  u16*   ob   = (u16*)carve((size_t)NTOK * DM * 2);
  u16*   ffb  = (u16*)carve((size_t)NTOK * DFF * 2);
  u16*   Wqkv = (u16*)carve((size_t)QKVW * DM * 2);
  float* bqkv = (float*)carve((size_t)QKVW * 4);
  u16*   WoT  = (u16*)carve((size_t)DM * DM * 2);
  u16*   W1T  = (u16*)carve((size_t)DFF * DM * 2);
  u16*   W2T  = (u16*)carve((size_t)DM * DFF * 2);
  u16*   tokb = (u16*)carve((size_t)NVP * DM * 2);   // 77.3 MB padded bf16 decoder

  scan_kernel<<<NB, 1024, 0, stream>>>(ids, rel, seg);
  embed_kernel<<<NTOK, 256, 0, stream>>>(ids, rel, tok, pos, x);
  tok2bf_kernel<<<(int)(((size_t)NVP * DM / 8 + 255) / 256), 256, 0, stream>>>(tok, tokb);

  for (int i = 0; i < NLAYERS; i++) {
    ln_kernel<<<NTOK, 256, 0, stream>>>(x, ln1g + (size_t)i * DM, ln1b + (size_t)i * DM, hb);
    repack_qkv<<<(QKVW * DM + 255) / 256, 256, 0, stream>>>(Wq, Wk, Wv, i, Wqkv);
    repack_bias<<<(QKVW + 255) / 256, 256, 0, stream>>>(bq, bk, bv, i, bqkv);
    launch_gemm(0, hb, Wqkv, bqkv, qkvb, NTOK, QKVW, DM, stream);
    attn_kernel<<<NB * NH * (SEQ / 64), 256, 0, stream>>>(qkvb, seg, ob);
    transpose_f2b<<<dim3(DM / 32, DM / 32), 256, 0, stream>>>(Wo + (size_t)i * DM * DM, WoT, DM, DM);
    launch_gemm(1, ob, WoT, bo + (size_t)i * DM, x, NTOK, DM, DM, stream);
    ln_kernel<<<NTOK, 256, 0, stream>>>(x, ln2g + (size_t)i * DM, ln2b + (size_t)i * DM, hb);
    transpose_f2b<<<dim3(DFF / 32, DM / 32), 256, 0, stream>>>(W1 + (size_t)i * DM * DFF, W1T, DM, DFF);
    launch_gemm(2, hb, W1T, b1 + (size_t)i * DFF, ffb, NTOK, DFF, DM, stream);
    transpose_f2b<<<dim3(DM / 32, DFF / 32), 256, 0, stream>>>(W2 + (size_t)i * DFF * DM, W2T, DFF, DM);
    launch_gemm(1, ffb, W2T, b2 + (size_t)i * DM, x, NTOK, DM, DFF, stream);
  }

  f2bf_kernel<<<(NTOK * DM + 255) / 256, 256, 0, stream>>>(x, hb, NTOK * DM);
  gemm_final<<<dim3((NTOK / 128) * (NVP / 128)), 256, 0, stream>>>(hb, tokb, (float*)d_out, NTOK, NV, DM);
}

// Round 4
// 1734.092 us; speedup vs baseline: 1.5911x; 1.0538x over previous
//
#include <hip/hip_runtime.h>

typedef unsigned short u16;
typedef unsigned int u32;
typedef __bf16 bf16x8 __attribute__((ext_vector_type(8)));
typedef float f32x4 __attribute__((ext_vector_type(4)));

#define EOS_ID 50256
#define DM 768
#define NH 12
#define DHD 64
#define SEQ 1024
#define NB 2
#define NLAYERS 4
#define DFF 3072
#define NV 50257
#define NVP 50304   // NV padded to multiple of 128
#define NTOK 2048
#define QKVW 2304

__device__ __forceinline__ float bf2f(u16 u) {
  union { float f; u32 u; } x; x.u = ((u32)u) << 16; return x.f;
}
__device__ __forceinline__ u16 f2bf(float f) {
  union { float f; u32 u; } x; x.f = f;
  u32 u = x.u;
  u += 0x7fffu + ((u >> 16) & 1u);   // round-to-nearest-even
  return (u16)(u >> 16);
}
__device__ __forceinline__ u32 pack2(float a, float b) {
  return (u32)f2bf(a) | ((u32)f2bf(b) << 16);
}

// async global->LDS, 16B per lane; LDS dest is wave-uniform base + lane*16
__device__ __forceinline__ void gload16(const u16* g, u16* l) {
  __builtin_amdgcn_global_load_lds(
      (const __attribute__((address_space(1))) unsigned int*)g,
      (__attribute__((address_space(3))) unsigned int*)l, 16, 0, 0);
}

// ---------- packed-segment scan ----------
__global__ __launch_bounds__(1024)
void scan_kernel(const int* __restrict__ ids, int* __restrict__ rel, int* __restrict__ seg) {
  __shared__ int sm[1024];
  __shared__ int ss[1024];
  const int b = blockIdx.x, t = threadIdx.x;
  const int e = (ids[b * SEQ + t] == EOS_ID) ? 1 : 0;
  sm[t] = e ? t : 0;
  ss[t] = e;
  __syncthreads();
  for (int o = 1; o < 1024; o <<= 1) {
    int vm = 0, vs = 0;
    if (t >= o) { vm = sm[t - o]; vs = ss[t - o]; }
    __syncthreads();
    if (t >= o) { if (vm > sm[t]) sm[t] = vm; ss[t] += vs; }
    __syncthreads();
  }
  rel[b * SEQ + t] = t - sm[t];
  seg[b * SEQ + t] = ss[t];
}

// ---------- embedding: x = tok[id]*sqrt(D) + pos[rel] (fp32 in, fp32 out) ----------
__global__ __launch_bounds__(256)
void embed_kernel(const int* __restrict__ ids, const int* __restrict__ rel,
                  const float* __restrict__ tok, const float* __restrict__ pos,
                  float* __restrict__ x) {
  const int row = blockIdx.x;
  const int id = ids[row];
  const int r = rel[row];
  const float s = 27.712812921102035f;  // sqrt(768)
  for (int d = threadIdx.x; d < DM; d += 256)
    x[(size_t)row * DM + d] = tok[(size_t)id * DM + d] * s + pos[(size_t)r * DM + d];
}

// ---------- tok fp32 [NV][DM] -> bf16 [NVP][DM], pad rows zeroed ----------
__global__ __launch_bounds__(256)
void tok2bf_kernel(const float* __restrict__ tok, u16* __restrict__ out) {
  const size_t i = ((size_t)blockIdx.x * 256 + threadIdx.x) * 8;
  if (i >= (size_t)NVP * DM) return;
  const size_t row = i / DM;
  uint4 o;
  if (row < NV) {
    const float4 f0 = *(const float4*)(tok + i);
    const float4 f1 = *(const float4*)(tok + i + 4);
    o = make_uint4(pack2(f0.x, f0.y), pack2(f0.z, f0.w), pack2(f1.x, f1.y), pack2(f1.z, f1.w));
  } else {
    o = make_uint4(0, 0, 0, 0);
  }
  *(uint4*)(out + i) = o;
}

// ---------- layernorm (fp32 in, fp32 gamma/beta) -> bf16 out ----------
__global__ __launch_bounds__(256)
void ln_kernel(const float* __restrict__ x, const float* __restrict__ g,
               const float* __restrict__ b, u16* __restrict__ out) {
  const int row = blockIdx.x, t = threadIdx.x;
  const int wave = t >> 6, lane = t & 63;
  const float* xr = x + (size_t)row * DM;
  float v0 = xr[t], v1 = xr[t + 256], v2 = xr[t + 512];
  __shared__ float red[4];
  float s = v0 + v1 + v2;
  for (int o = 32; o; o >>= 1) s += __shfl_down(s, o, 64);
  if (lane == 0) red[wave] = s;
  __syncthreads();
  const float mean = (red[0] + red[1] + red[2] + red[3]) * (1.f / DM);
  __syncthreads();
  const float a0 = v0 - mean, a1 = v1 - mean, a2 = v2 - mean;
  float s2 = a0 * a0 + a1 * a1 + a2 * a2;
  for (int o = 32; o; o >>= 1) s2 += __shfl_down(s2, o, 64);
  if (lane == 0) red[wave] = s2;
  __syncthreads();
  const float var = (red[0] + red[1] + red[2] + red[3]) * (1.f / DM);
  const float rstd = rsqrtf(var + 1e-5f);
  u16* orow = out + (size_t)row * DM;
  orow[t]       = f2bf(a0 * rstd * g[t]       + b[t]);
  orow[t + 256] = f2bf(a1 * rstd * g[t + 256] + b[t + 256]);
  orow[t + 512] = f2bf(a2 * rstd * g[t + 512] + b[t + 512]);
}

// ---------- repack Wq/Wk/Wv fp32 [H,D,DH] -> fused bf16 B^T [2304][768] ----------
// Coalesced via 32x32 LDS tile transpose. grid = (DHD/32, DM/32, 3*NH).
__global__ __launch_bounds__(256)
void repack_qkv(const float* __restrict__ Wq, const float* __restrict__ Wk,
                const float* __restrict__ Wv, int layer, u16* __restrict__ out) {
  __shared__ float tile[32][33];
  const int z = blockIdx.z;
  const int sel = z / NH, hh = z % NH;
  const float* W = ((sel == 0) ? Wq : (sel == 1) ? Wk : Wv) +
                   ((size_t)layer * NH + hh) * DM * DHD;
  const int k0 = blockIdx.y * 32;
  const int d0 = blockIdx.x * 32;
  const int tx = threadIdx.x & 31, ty = threadIdx.x >> 5;
  for (int i = 0; i < 32; i += 8)
    tile[ty + i][tx] = W[(size_t)(k0 + ty + i) * DHD + d0 + tx];
  __syncthreads();
  u16* dst = out + ((size_t)sel * DM + hh * DHD + d0) * DM + k0;
  for (int i = 0; i < 32; i += 8)
    dst[(size_t)(ty + i) * DM + tx] = f2bf(tile[tx][ty + i]);
}

__global__ __launch_bounds__(256)
void repack_bias(const float* __restrict__ bq, const float* __restrict__ bk,
                 const float* __restrict__ bv, int layer, float* __restrict__ out) {
  const int n = blockIdx.x * 256 + threadIdx.x;
  if (n >= QKVW) return;
  const int sel = n / DM;
  const int hh = (n % DM) / DHD, dh = n % DHD;
  const float* B = (sel == 0) ? bq : (sel == 1) ? bk : bv;
  out[n] = B[((size_t)layer * NH + hh) * DHD + dh];
}

// ---------- transpose fp32 [R][C] -> bf16 [C][R] (R,C multiples of 32) ----------
__global__ __launch_bounds__(256)
void transpose_f2b(const float* __restrict__ src, u16* __restrict__ dst, int R, int C) {
  __shared__ float tile[32][33];
  const int c0 = blockIdx.x * 32, r0 = blockIdx.y * 32;
  const int tx = threadIdx.x & 31, ty = threadIdx.x >> 5;
  for (int i = 0; i < 32; i += 8)
    tile[ty + i][tx] = src[(size_t)(r0 + ty + i) * C + c0 + tx];
  __syncthreads();
  for (int i = 0; i < 32; i += 8)
    dst[(size_t)(c0 + ty + i) * R + r0 + tx] = f2bf(tile[tx][ty + i]);
}

// ---------- fp32 -> bf16 ----------
__global__ __launch_bounds__(256)
void f2bf_kernel(const float* __restrict__ in, u16* __restrict__ out, int n) {
  const int i = blockIdx.x * 256 + threadIdx.x;
  if (i < n) out[i] = f2bf(in[i]);
}

// ---------- GEMM: C[M,N] = A[M,K] @ BT[N,K]^T (bf16 in, fp32 acc, fp32 bias) ----------
// 2-phase prefetch: double-buffered [128][32] LDS, global_load_lds width=16,
// counted vmcnt(4) (next-tile loads stay in flight across barriers).
// All callers have M,N multiples of 128 and K multiple of 32.
// EPI 0: bf16 = acc+bias ; EPI 1: fp32 += acc+bias ; EPI 2: bf16 gelu(acc+bias)
template <int EPI>
__global__ __launch_bounds__(256)
void gemm_bt(const u16* __restrict__ A, const u16* __restrict__ BT,
             const float* __restrict__ bias, void* __restrict__ out,
             const int M, const int N, const int K) {
  __shared__ u16 As[2][128 * 32];
  __shared__ u16 Bs[2][128 * 32];
  const int t = threadIdx.x;
  const int wave = t >> 6, lane = t & 63;
  const int l15 = lane & 15, quad = lane >> 4;
  const int wm = wave >> 1, wn = wave & 1;
  const int m0 = blockIdx.y * 128;
  const int n0 = blockIdx.x * 128;

  const int rsub = lane >> 2;          // 0..15: row within 16-row group
  const int cseg = (lane & 3) * 8;     // u16 col offset (16B per lane)
  const u16* gA0 = A + (size_t)(m0 + wave * 32 + rsub) * K + cseg;
  const u16* gA1 = gA0 + (size_t)16 * K;
  const u16* gB0 = BT + (size_t)(n0 + wave * 32 + rsub) * K + cseg;
  const u16* gB1 = gB0 + (size_t)16 * K;

  f32x4 acc[4][4] = {};
  const int nt = K >> 5;

  // prologue
  gload16(gA0, &As[0][(wave * 32) * 32]);
  gload16(gA1, &As[0][(wave * 32 + 16) * 32]);
  gload16(gB0, &Bs[0][(wave * 32) * 32]);
  gload16(gB1, &Bs[0][(wave * 32 + 16) * 32]);

  int cur = 0;
  for (int tt = 0; tt < nt; tt++) {
    if (tt + 1 < nt) {
      const int k1 = (tt + 1) << 5;
      const int nb = cur ^ 1;
      gload16(gA0 + k1, &As[nb][(wave * 32) * 32]);
      gload16(gA1 + k1, &As[nb][(wave * 32 + 16) * 32]);
      gload16(gB0 + k1, &Bs[nb][(wave * 32) * 32]);
      gload16(gB1 + k1, &Bs[nb][(wave * 32 + 16) * 32]);
      asm volatile("s_waitcnt vmcnt(4)" ::: "memory");
    } else {
      asm volatile("s_waitcnt vmcnt(0)" ::: "memory");
    }
    __builtin_amdgcn_s_barrier();
    __builtin_amdgcn_sched_barrier(0);
    bf16x8 af[4], bfr[4];
#pragma unroll
    for (int mt = 0; mt < 4; mt++)
      af[mt] = *(const bf16x8*)&As[cur][(wm * 64 + mt * 16 + l15) * 32 + quad * 8];
#pragma unroll
    for (int nn = 0; nn < 4; nn++)
      bfr[nn] = *(const bf16x8*)&Bs[cur][(wn * 64 + nn * 16 + l15) * 32 + quad * 8];
#pragma unroll
    for (int mt = 0; mt < 4; mt++)
#pragma unroll
      for (int nn = 0; nn < 4; nn++)
        acc[mt][nn] = __builtin_amdgcn_mfma_f32_16x16x32_bf16(af[mt], bfr[nn], acc[mt][nn], 0, 0, 0);
    __builtin_amdgcn_sched_barrier(0);
    __builtin_amdgcn_s_barrier();
    cur ^= 1;
  }

#pragma unroll
  for (int nn = 0; nn < 4; nn++) {
    const int n = n0 + wn * 64 + nn * 16 + l15;
    const float bvv = bias ? bias[n] : 0.f;
#pragma unroll
    for (int mt = 0; mt < 4; mt++) {
      const int mb = m0 + wm * 64 + mt * 16 + quad * 4;
#pragma unroll
      for (int r = 0; r < 4; r++) {
        const size_t idx = (size_t)(mb + r) * N + n;
        const float v = acc[mt][nn][r] + bvv;
        if (EPI == 0) {
          ((u16*)out)[idx] = f2bf(v);
        } else if (EPI == 1) {
          ((float*)out)[idx] += v;
        } else {
          const float gg = 0.5f * v * (1.f + erff(v * 0.70710678118654752f));
          ((u16*)out)[idx] = f2bf(gg);
        }
      }
    }
  }
}

// ---------- final GEMM: out fp32 [M,NV] = A(bf16)[M,K] @ tokb(bf16)[NVP,K]^T ----------
// XCD-swizzled 1-D grid (M-tile fastest) + 2-phase prefetch K-loop +
// LDS-staged epilogue for full-line 256B stores.
__global__ __launch_bounds__(256)
void gemm_final(const u16* __restrict__ A, const u16* __restrict__ BT,
                float* __restrict__ out, const int M, const int N, const int K) {
  __shared__ u16 smem[2][2][128 * 32];   // 32 KB: [A/B][dbuf]; epilogue scratch aliases
  const int t = threadIdx.x;
  const int wave = t >> 6, lane = t & 63;
  const int l15 = lane & 15, quad = lane >> 4;
  const int wm = wave >> 1, wn = wave & 1;

  // XCD swizzle: gridDim.x = 16*393 = 6288, divisible by 8.
  const int bid = blockIdx.x;
  const int nper = gridDim.x >> 3;
  const int gt = (bid & 7) * nper + (bid >> 3);
  const int mtile = gt & 15;
  const int ntile = gt >> 4;
  const int m0 = mtile * 128;
  const int n0 = ntile * 128;

  const int rsub = lane >> 2;
  const int cseg = (lane & 3) * 8;
  const u16* gA0 = A + (size_t)(m0 + wave * 32 + rsub) * K + cseg;
  const u16* gA1 = gA0 + (size_t)16 * K;
  const u16* gB0 = BT + (size_t)(n0 + wave * 32 + rsub) * K + cseg;
  const u16* gB1 = gB0 + (size_t)16 * K;

  f32x4 acc[4][4] = {};
  const int nt = K >> 5;

  gload16(gA0, &smem[0][0][(wave * 32) * 32]);
  gload16(gA1, &smem[0][0][(wave * 32 + 16) * 32]);
  gload16(gB0, &smem[1][0][(wave * 32) * 32]);
  gload16(gB1, &smem[1][0][(wave * 32 + 16) * 32]);

  int cur = 0;
  for (int tt = 0; tt < nt; tt++) {
    if (tt + 1 < nt) {
      const int k1 = (tt + 1) << 5;
      const int nb = cur ^ 1;
      gload16(gA0 + k1, &smem[0][nb][(wave * 32) * 32]);
      gload16(gA1 + k1, &smem[0][nb][(wave * 32 + 16) * 32]);
      gload16(gB0 + k1, &smem[1][nb][(wave * 32) * 32]);
      gload16(gB1 + k1, &smem[1][nb][(wave * 32 + 16) * 32]);
      asm volatile("s_waitcnt vmcnt(4)" ::: "memory");
    } else {
      asm volatile("s_waitcnt vmcnt(0)" ::: "memory");
    }
    __builtin_amdgcn_s_barrier();
    __builtin_amdgcn_sched_barrier(0);
    bf16x8 af[4], bfr[4];
#pragma unroll
    for (int mt = 0; mt < 4; mt++)
      af[mt] = *(const bf16x8*)&smem[0][cur][(wm * 64 + mt * 16 + l15) * 32 + quad * 8];
#pragma unroll
    for (int nn = 0; nn < 4; nn++)
      bfr[nn] = *(const bf16x8*)&smem[1][cur][(wn * 64 + nn * 16 + l15) * 32 + quad * 8];
#pragma unroll
    for (int mt = 0; mt < 4; mt++)
#pragma unroll
      for (int nn = 0; nn < 4; nn++)
        acc[mt][nn] = __builtin_amdgcn_mfma_f32_16x16x32_bf16(af[mt], bfr[nn], acc[mt][nn], 0, 0, 0);
    __builtin_amdgcn_sched_barrier(0);
    __builtin_amdgcn_s_barrier();
    cur ^= 1;
  }

  // epilogue: stage per-mt slice (32 rows x 128 cols fp32, stride 132) in LDS,
  // then 64 consecutive lanes write 256 B contiguous per store (full L2 lines).
  float* sc = (float*)smem;  // 32*132*4 = 16896 B <= 32768 B
  for (int mt = 0; mt < 4; mt++) {
    __syncthreads();
#pragma unroll
    for (int nn = 0; nn < 4; nn++)
#pragma unroll
      for (int r = 0; r < 4; r++)
        sc[(wm * 16 + quad * 4 + r) * 132 + wn * 64 + nn * 16 + l15] = acc[mt][nn][r];
    __syncthreads();
#pragma unroll
    for (int it = 0; it < 16; it++) {
      const int lin = it * 256 + t;          // 0..4095
      const int s = lin >> 7;                // staged row 0..31
      const int c = lin & 127;               // col within tile
      const int grow = m0 + mt * 16 + (s & 15) + (s >> 4) * 64;
      const int gcol = n0 + c;
      if (gcol < N) out[(size_t)grow * N + gcol] = sc[s * 132 + c];
    }
  }
}

// ---------- MFMA flash attention ----------
// Block = (b, h, 64 q-rows); 4 waves x 16 q-rows; KV chunks of 32.
// Swapped QK^T: S^T[kv][q] = mfma(K_frag, Q_frag) -> softmax state lane-local at q=l15.
// PV as O^T = V^T @ P: C[d][q=l15] keeps rescale per-lane. V^T and P staged in LDS
// (stride 40 u16: 16B-aligned b128 reads, ~2-way banks). K/V prefetched 1 chunk ahead.
__global__ __launch_bounds__(256)
void attn_kernel(const u16* __restrict__ qkv, const int* __restrict__ seg,
                 u16* __restrict__ ob) {
  __shared__ int seg_lds[SEQ];
  __shared__ u16 VT[64 * 40];       // V^T tile [d][kv], row stride 40 u16
  __shared__ u16 PL[4][16 * 40];    // per-wave P [q][kv], row stride 40 u16

  const int t = threadIdx.x;
  const int wave = t >> 6, lane = t & 63;
  const int l15 = lane & 15, quad = lane >> 4;
  const int bid = blockIdx.x;
  const int qb = bid & 15;
  const int hh = (bid >> 4) % NH;
  const int b = (bid >> 4) / NH;
  const size_t rowbase = (size_t)b * SEQ;
  const int kvmax = (qb + 1) * 64;
  const int qw0 = qb * 64 + wave * 16;   // wave's first q row

  for (int idx = t; idx < kvmax; idx += 256) seg_lds[idx] = seg[b * SEQ + idx];

  // Q fragments: lane holds Q[qw0+l15][d = half*32 + quad*8 .. +7]
  const u16* qrow = qkv + (rowbase + qw0 + l15) * QKVW + hh * DHD;
  const bf16x8 qf0 = *(const bf16x8*)(qrow + quad * 8);
  const bf16x8 qf1 = *(const bf16x8*)(qrow + 32 + quad * 8);

  __syncthreads();
  const int si = seg_lds[qw0 + l15];

  const int vkv = t >> 3;          // 0..31 (kv row within chunk)
  const int vdd = (t & 7) * 8;     // d offset, 16B per thread
  const u16* vbase = qkv + rowbase * QKVW + 2 * DM + hh * DHD + vdd;
  const u16* kbase = qkv + rowbase * QKVW + DM + hh * DHD;

  // prefetch chunk 0
  uint4 vld = *(const uint4*)(vbase + (size_t)vkv * QKVW);
  uint4 kfa = *(const uint4*)(kbase + (size_t)l15 * QKVW + quad * 8);
  uint4 kfb = *(const uint4*)(kbase + (size_t)l15 * QKVW + 32 + quad * 8);
  uint4 kfc = *(const uint4*)(kbase + (size_t)(16 + l15) * QKVW + quad * 8);
  uint4 kfd = *(const uint4*)(kbase + (size_t)(16 + l15) * QKVW + 32 + quad * 8);

  f32x4 o0 = {}, o1 = {}, o2 = {}, o3 = {};
  float mrun = -1e30f, lrun = 0.f;

  const int nch = kvmax >> 5;
  for (int c = 0; c < nch; c++) {
    const int j0 = c << 5;
    __syncthreads();               // prev chunk's VT reads complete
    {
      const u16* pv = (const u16*)&vld;
#pragma unroll
      for (int jj = 0; jj < 8; jj++) VT[(vdd + jj) * 40 + vkv] = pv[jj];
    }
    __syncthreads();               // VT ready
    // prefetch next chunk (last iter re-loads current; harmless)
    const int j1 = (c + 1 < nch) ? j0 + 32 : j0;
    uint4 vld_n = *(const uint4*)(vbase + (size_t)(j1 + vkv) * QKVW);
    uint4 kfa_n = *(const uint4*)(kbase + (size_t)(j1 + l15) * QKVW + quad * 8);
    uint4 kfb_n = *(const uint4*)(kbase + (size_t)(j1 + l15) * QKVW + 32 + quad * 8);
    uint4 kfc_n = *(const uint4*)(kbase + (size_t)(j1 + 16 + l15) * QKVW + quad * 8);
    uint4 kfd_n = *(const uint4*)(kbase + (size_t)(j1 + 16 + l15) * QKVW + 32 + quad * 8);

    // S^T tiles: S^T[kv = quad*4+r (+16)][q = l15], accumulate over d halves
    f32x4 s0 = {}, s1 = {};
    s0 = __builtin_amdgcn_mfma_f32_16x16x32_bf16(*(const bf16x8*)&kfa, qf0, s0, 0, 0, 0);
    s0 = __builtin_amdgcn_mfma_f32_16x16x32_bf16(*(const bf16x8*)&kfb, qf1, s0, 0, 0, 0);
    s1 = __builtin_amdgcn_mfma_f32_16x16x32_bf16(*(const bf16x8*)&kfc, qf0, s1, 0, 0, 0);
    s1 = __builtin_amdgcn_mfma_f32_16x16x32_bf16(*(const bf16x8*)&kfd, qf1, s1, 0, 0, 0);

    const int iq = qw0 + l15;
    float p[8];
    float cmax = -1e30f;
#pragma unroll
    for (int r = 0; r < 4; r++) {
      int j = j0 + quad * 4 + r;
      bool ok = (j <= iq) && (seg_lds[j] == si);
      float sv = ok ? s0[r] : -1e30f;
      p[r] = sv; cmax = fmaxf(cmax, sv);
      j += 16;
      ok = (j <= iq) && (seg_lds[j] == si);
      sv = ok ? s1[r] : -1e30f;
      p[4 + r] = sv; cmax = fmaxf(cmax, sv);
    }
    // reduce over the 4 quad-replicas of each q (lanes l15, +16, +32, +48)
    cmax = fmaxf(cmax, __shfl_xor(cmax, 16, 64));
    cmax = fmaxf(cmax, __shfl_xor(cmax, 32, 64));
    const float mnew = fmaxf(mrun, cmax);
    const float fsc = __expf(mrun - mnew);   // <= 1 always; exp(0)=1 if unchanged
    mrun = mnew;
    float csum = 0.f;
#pragma unroll
    for (int r = 0; r < 8; r++) {
      const float e = (p[r] > -5e29f) ? __expf(p[r] - mnew) : 0.f;  // masked -> exactly 0
      p[r] = e; csum += e;
    }
    csum += __shfl_xor(csum, 16, 64);
    csum += __shfl_xor(csum, 32, 64);
    lrun = lrun * fsc + csum;
#pragma unroll
    for (int r = 0; r < 4; r++) { o0[r] *= fsc; o1[r] *= fsc; o2[r] *= fsc; o3[r] *= fsc; }

    // bounce P through wave-private LDS: [q=l15][kv] layout, kv contiguous
    u32* plw = (u32*)&PL[wave][l15 * 40 + quad * 4];
    plw[0] = pack2(p[0], p[1]);
    plw[1] = pack2(p[2], p[3]);
    u32* plw2 = (u32*)&PL[wave][l15 * 40 + 16 + quad * 4];
    plw2[0] = pack2(p[4], p[5]);
    plw2[1] = pack2(p[6], p[7]);

    // fragments: P^T rows (q=l15) and V^T rows (d), k = kv = quad*8..+7
    const bf16x8 pf = *(const bf16x8*)&PL[wave][l15 * 40 + quad * 8];
    const bf16x8 va = *(const bf16x8*)&VT[(l15) * 40 + quad * 8];
    const bf16x8 vb = *(const bf16x8*)&VT[(16 + l15) * 40 + quad * 8];
    const bf16x8 vc = *(const bf16x8*)&VT[(32 + l15) * 40 + quad * 8];
    const bf16x8 vd8 = *(const bf16x8*)&VT[(48 + l15) * 40 + quad * 8];
    o0 = __builtin_amdgcn_mfma_f32_16x16x32_bf16(va, pf, o0, 0, 0, 0);
    o1 = __builtin_amdgcn_mfma_f32_16x16x32_bf16(vb, pf, o1, 0, 0, 0);
    o2 = __builtin_amdgcn_mfma_f32_16x16x32_bf16(vc, pf, o2, 0, 0, 0);
    o3 = __builtin_amdgcn_mfma_f32_16x16x32_bf16(vd8, pf, o3, 0, 0, 0);

    vld = vld_n; kfa = kfa_n; kfb = kfb_n; kfc = kfc_n; kfd = kfd_n;
  }

  // O^T layout: o_mt[r] = O[q = qw0+l15][d = mt*16 + quad*4 + r]
  const float inv = 1.f / lrun;
  u16* orow = ob + (rowbase + qw0 + l15) * DM + hh * DHD;
#pragma unroll
  for (int r = 0; r < 4; r++) {
    orow[quad * 4 + r]      = f2bf(o0[r] * inv);
    orow[16 + quad * 4 + r] = f2bf(o1[r] * inv);
    orow[32 + quad * 4 + r] = f2bf(o2[r] * inv);
    orow[48 + quad * 4 + r] = f2bf(o3[r] * inv);
  }
}

static inline void launch_gemm(int epi, const u16* A, const u16* BT, const float* bias,
                               void* out, int M, int N, int K, hipStream_t s) {
  dim3 g(N / 128, M / 128);
  if (epi == 0)      gemm_bt<0><<<g, 256, 0, s>>>(A, BT, bias, out, M, N, K);
  else if (epi == 1) gemm_bt<1><<<g, 256, 0, s>>>(A, BT, bias, out, M, N, K);
  else               gemm_bt<2><<<g, 256, 0, s>>>(A, BT, bias, out, M, N, K);
}

extern "C" void kernel_launch(void* const* d_in, const int* in_sizes, int n_in,
                              void* d_out, int out_size, void* d_ws, size_t ws_size,
                              hipStream_t stream) {
  (void)in_sizes; (void)n_in; (void)out_size; (void)ws_size;
  const int*   ids  = (const int*)d_in[0];
  const float* tok  = (const float*)d_in[1];
  const float* pos  = (const float*)d_in[2];
  const float* ln1g = (const float*)d_in[3];
  const float* ln1b = (const float*)d_in[4];
  const float* Wq   = (const float*)d_in[5];
  const float* bq   = (const float*)d_in[6];
  const float* Wk   = (const float*)d_in[7];
  const float* bk   = (const float*)d_in[8];
  const float* Wv   = (const float*)d_in[9];
  const float* bv   = (const float*)d_in[10];
  const float* Wo   = (const float*)d_in[11];
  const float* bo   = (const float*)d_in[12];
  const float* ln2g = (const float*)d_in[13];
  const float* ln2b = (const float*)d_in[14];
  const float* W1   = (const float*)d_in[15];
  const float* b1   = (const float*)d_in[16];
  const float* W2   = (const float*)d_in[17];
  const float* b2   = (const float*)d_in[18];

  char* w = (char*)d_ws;
  auto carve = [&](size_t bytes) -> char* {
    char* p = w;
    w += (bytes + 255) & ~(size_t)255;
    return p;
  };
  int*   rel  = (int*)carve((size_t)NTOK * 4);
  int*   seg  = (int*)carve((size_t)NTOK * 4);
  float* x    = (float*)carve((size_t)NTOK * DM * 4);
  u16*   hb   = (u16*)carve((size_t)NTOK * DM * 2);
  u16*   qkvb = (u16*)carve((size_t)NTOK * QKVW * 2);
  u16*   ob   = (u16*)carve((size_t)NTOK * DM * 2);
  u16*   ffb  = (u16*)carve((size_t)NTOK * DFF * 2);
  u16*   Wqkv = (u16*)carve((size_t)QKVW * DM * 2);
  float* bqkv = (float*)carve((size_t)QKVW * 4);
  u16*   WoT  = (u16*)carve((size_t)DM * DM * 2);
  u16*   W1T  = (u16*)carve((size_t)DFF * DM * 2);
  u16*   W2T  = (u16*)carve((size_t)DM * DFF * 2);
  u16*   tokb = (u16*)carve((size_t)NVP * DM * 2);   // 77.3 MB padded bf16 decoder

  scan_kernel<<<NB, 1024, 0, stream>>>(ids, rel, seg);
  embed_kernel<<<NTOK, 256, 0, stream>>>(ids, rel, tok, pos, x);
  tok2bf_kernel<<<(int)(((size_t)NVP * DM / 8 + 255) / 256), 256, 0, stream>>>(tok, tokb);

  for (int i = 0; i < NLAYERS; i++) {
    ln_kernel<<<NTOK, 256, 0, stream>>>(x, ln1g + (size_t)i * DM, ln1b + (size_t)i * DM, hb);
    repack_qkv<<<dim3(DHD / 32, DM / 32, 3 * NH), 256, 0, stream>>>(Wq, Wk, Wv, i, Wqkv);
    repack_bias<<<(QKVW + 255) / 256, 256, 0, stream>>>(bq, bk, bv, i, bqkv);
    launch_gemm(0, hb, Wqkv, bqkv, qkvb, NTOK, QKVW, DM, stream);
    attn_kernel<<<NB * NH * (SEQ / 64), 256, 0, stream>>>(qkvb, seg, ob);
    transpose_f2b<<<dim3(DM / 32, DM / 32), 256, 0, stream>>>(Wo + (size_t)i * DM * DM, WoT, DM, DM);
    launch_gemm(1, ob, WoT, bo + (size_t)i * DM, x, NTOK, DM, DM, stream);
    ln_kernel<<<NTOK, 256, 0, stream>>>(x, ln2g + (size_t)i * DM, ln2b + (size_t)i * DM, hb);
    transpose_f2b<<<dim3(DFF / 32, DM / 32), 256, 0, stream>>>(W1 + (size_t)i * DM * DFF, W1T, DM, DFF);
    launch_gemm(2, hb, W1T, b1 + (size_t)i * DFF, ffb, NTOK, DFF, DM, stream);
    transpose_f2b<<<dim3(DM / 32, DFF / 32), 256, 0, stream>>>(W2 + (size_t)i * DFF * DM, W2T, DFF, DM);
    launch_gemm(1, ffb, W2T, b2 + (size_t)i * DM, x, NTOK, DM, DFF, stream);
  }

  f2bf_kernel<<<(NTOK * DM + 255) / 256, 256, 0, stream>>>(x, hb, NTOK * DM);
  gemm_final<<<dim3((NTOK / 128) * (NVP / 128)), 256, 0, stream>>>(hb, tokb, (float*)d_out, NTOK, NV, DM);
}